// Round 8
// baseline (319.879 us; speedup 1.0000x reference)
//
#include <hip/hip_runtime.h>
#include <hip/hip_bf16.h>

// GCN encoder: 2x GCNConv, symmetric norm, relu + L2 rownorm between.
// Pull aggregation over CSR-by-dst, bf16 intermediates (f32 accumulate).
// R7: CSR built with ZERO global atomics (LDS histograms + scans).
// R8: agg loops fully batched; dinv[src] folded into GEMM epilogue.
// R9: GEMMs on MFMA 16x16x32 bf16, hi/lo split (f32-equiv accuracy).
// R10: B staged in XOR-swizzled LDS; 2 row-tiles/wave. GEMMs off the radar.
// R11: agg1 16B/lane gather: NEUTRAL => not VALU-bound.
// R12: 4 gather chains: +5% only => ~3.5 TB/s L2-miss-path ceiling; MLP and
//      issue-rate are NOT the levers. Bytes/hit-rate are.
// R13 (this round): agg1 split into TWO sequential channel-half passes.
// Rows are 2x128B lines, channel-disjoint: pass H gathers only line H of
// every row => per-pass working set 25.6->12.8 MB => per-XCD L2 coverage
// doubles => fewer misses. L2-norm coupling solved by storing h PRE-norm
// (same single bf16 rounding; scale-invariant) + per-pass ss partials;
// scale folded into gemm2 epilogue: rowscale2 = dinv / max(sqrt(ssA+ssB),eps).

#define IN_CH 128
#define HID 128
#define OUT_CH 64
#define NBLK 128          // chunk blocks for hist/scatter
#define MAXNB 1568        // >= ceil(100000/64)=1563 buckets

typedef unsigned int uint_t;
typedef unsigned short ushort_t;
typedef __attribute__((ext_vector_type(8))) short bf16x8;
typedef __attribute__((ext_vector_type(4))) float f32x4;
typedef __attribute__((ext_vector_type(2))) float f32v2;

__device__ __forceinline__ ushort_t f32_to_bf16_rn(float f) {
    uint_t u = __float_as_uint(f);
    u = (u + 0x7fffu + ((u >> 16) & 1u)) >> 16;
    return (ushort_t)u;
}
__device__ __forceinline__ float bf16lo_to_f32(uint_t u) { return __uint_as_float(u << 16); }
__device__ __forceinline__ float bf16hi_to_f32(uint_t u) { return __uint_as_float(u & 0xffff0000u); }

// accumulate one 16B row-chunk (8 bf16 channels) into 4 f32v2 accumulators
__device__ __forceinline__ void acc_row(f32v2& a0, f32v2& a1, f32v2& a2, f32v2& a3,
                                        uint4 v) {
    a0 += (f32v2){bf16lo_to_f32(v.x), bf16hi_to_f32(v.x)};
    a1 += (f32v2){bf16lo_to_f32(v.y), bf16hi_to_f32(v.y)};
    a2 += (f32v2){bf16lo_to_f32(v.z), bf16hi_to_f32(v.z)};
    a3 += (f32v2){bf16lo_to_f32(v.w), bf16hi_to_f32(v.w)};
}
__device__ __forceinline__ void acc_row_c(f32v2& a0, f32v2& a1, f32v2& a2, f32v2& a3,
                                          uint4 v, float c) {
    f32v2 cv = {c, c};
    a0 += (f32v2){bf16lo_to_f32(v.x), bf16hi_to_f32(v.x)} * cv;
    a1 += (f32v2){bf16lo_to_f32(v.y), bf16hi_to_f32(v.y)} * cv;
    a2 += (f32v2){bf16lo_to_f32(v.z), bf16hi_to_f32(v.z)} * cv;
    a3 += (f32v2){bf16lo_to_f32(v.w), bf16hi_to_f32(v.w)} * cv;
}

// ---------------- phase 1: per-block LDS bucket histogram ----------------
__global__ __launch_bounds__(256) void hist_kernel(const int* __restrict__ dst, int E,
                                                   int chunk, int NB,
                                                   int* __restrict__ blk_cnt) {
    __shared__ int hist[MAXNB];
    int tid = threadIdx.x;
    int blk = blockIdx.x;
    for (int b = tid; b < NB; b += 256) hist[b] = 0;
    __syncthreads();
    int start = blk * chunk;
    int end = start + chunk; if (end > E) end = E;
    int e = start + tid;
    for (; e + 768 < end; e += 1024) {
        int d0 = dst[e], d1 = dst[e + 256], d2 = dst[e + 512], d3 = dst[e + 768];
        atomicAdd(&hist[d0 >> 6], 1);
        atomicAdd(&hist[d1 >> 6], 1);
        atomicAdd(&hist[d2 >> 6], 1);
        atomicAdd(&hist[d3 >> 6], 1);
    }
    for (; e < end; e += 256) atomicAdd(&hist[dst[e] >> 6], 1);
    __syncthreads();
    for (int b = tid; b < NB; b += 256) blk_cnt[blk * NB + b] = hist[b];
}

// ---------------- phase 2a: bucket totals (column sums) ----------------
__global__ __launch_bounds__(256) void btot_kernel(const int* __restrict__ blk_cnt,
                                                   int NB, int* __restrict__ btot) {
    int b = blockIdx.x * 256 + threadIdx.x;
    if (b < NB) {
        int sum = 0;
        #pragma unroll 8
        for (int blk = 0; blk < NBLK; blk++) sum += blk_cnt[blk * NB + b];
        btot[b] = sum;
    }
}

// ---------------- phase 2b: single-block exclusive scan over buckets --------------
__global__ __launch_bounds__(256) void scan_kernel(const int* __restrict__ btot, int NB,
                                                   int* __restrict__ bucket_base,
                                                   int* __restrict__ row_start,
                                                   int n, int E) {
    __shared__ int sdata[256];
    __shared__ int carryS;
    int tid = threadIdx.x;
    if (tid == 0) carryS = 0;
    __syncthreads();
    int nchunks = (NB + 255) / 256;
    for (int c = 0; c < nchunks; c++) {
        int i = c * 256 + tid;
        int v = (i < NB) ? btot[i] : 0;
        sdata[tid] = v;
        __syncthreads();
        for (int off = 1; off < 256; off <<= 1) {
            int t = (tid >= off) ? sdata[tid - off] : 0;
            __syncthreads();
            sdata[tid] += t;
            __syncthreads();
        }
        if (i < NB) bucket_base[i] = carryS + sdata[tid] - v;
        __syncthreads();
        if (tid == 0) carryS += sdata[255];
        __syncthreads();
    }
    if (tid == 0) {
        bucket_base[NB] = E;
        row_start[n] = E;
    }
}

// ---------------- phase 2c: per-bucket exclusive scan over blocks -----------------
__global__ __launch_bounds__(256) void colscan_kernel(const int* __restrict__ blk_cnt,
                                                      const int* __restrict__ bucket_base,
                                                      int NB, int* __restrict__ blk_start) {
    __shared__ int tile[NBLK][16];
    int tid = threadIdx.x;
    int b0 = blockIdx.x * 16;
    for (int idx = tid; idx < NBLK * 16; idx += 256) {
        int blk = idx >> 4, b = idx & 15;
        if (b0 + b < NB) tile[blk][b] = blk_cnt[blk * NB + b0 + b];
    }
    __syncthreads();
    if (tid < 16 && b0 + tid < NB) {
        int running = bucket_base[b0 + tid];
        for (int blk = 0; blk < NBLK; blk++) {
            int t = tile[blk][tid];
            tile[blk][tid] = running;
            running += t;
        }
    }
    __syncthreads();
    for (int idx = tid; idx < NBLK * 16; idx += 256) {
        int blk = idx >> 4, b = idx & 15;
        if (b0 + b < NB) blk_start[blk * NB + b0 + b] = tile[blk][b];
    }
}

// ---------------- phase 3: scatter, LDS tickets only ----------------
// pack: src (26 bits) | (dst & 63) << 26.
__global__ __launch_bounds__(256) void scatter_kernel(const int* __restrict__ src,
                                                      const int* __restrict__ dst,
                                                      int E, int chunk, int NB,
                                                      const int* __restrict__ blk_start,
                                                      uint_t* __restrict__ pairs) {
    __shared__ int cur[MAXNB];
    int tid = threadIdx.x;
    int blk = blockIdx.x;
    for (int b = tid; b < NB; b += 256) cur[b] = blk_start[blk * NB + b];
    __syncthreads();
    int start = blk * chunk;
    int end = start + chunk; if (end > E) end = E;
    int e = start + tid;
    for (; e + 768 < end; e += 1024) {
        int d0 = dst[e], d1 = dst[e + 256], d2 = dst[e + 512], d3 = dst[e + 768];
        int s0 = src[e], s1 = src[e + 256], s2 = src[e + 512], s3 = src[e + 768];
        int p0 = atomicAdd(&cur[d0 >> 6], 1);
        int p1 = atomicAdd(&cur[d1 >> 6], 1);
        int p2 = atomicAdd(&cur[d2 >> 6], 1);
        int p3 = atomicAdd(&cur[d3 >> 6], 1);
        pairs[p0] = (uint_t)s0 | ((uint_t)(d0 & 63) << 26);
        pairs[p1] = (uint_t)s1 | ((uint_t)(d1 & 63) << 26);
        pairs[p2] = (uint_t)s2 | ((uint_t)(d2 & 63) << 26);
        pairs[p3] = (uint_t)s3 | ((uint_t)(d3 & 63) << 26);
    }
    for (; e < end; e += 256) {
        int d = dst[e], s = src[e];
        int p = atomicAdd(&cur[d >> 6], 1);
        pairs[p] = (uint_t)s | ((uint_t)(d & 63) << 26);
    }
}

// ---------------- phase 4: fine fill -- per bucket: counts, row_start, dinv, csr ---
__global__ __launch_bounds__(256) void fine_fill_kernel(const uint_t* __restrict__ pairs,
                                                        const int* __restrict__ bucket_base,
                                                        int* __restrict__ row_start,
                                                        float* __restrict__ dinv,
                                                        int* __restrict__ csr_src,
                                                        int n) {
    __shared__ int cnt64[64];
    __shared__ int cur[64];
    int b = blockIdx.x;
    int node0 = b << 6;
    int tid = threadIdx.x;
    if (tid < 64) cnt64[tid] = 0;
    __syncthreads();
    int start = bucket_base[b];
    int end = bucket_base[b + 1];
    int e = start + tid;
    for (; e + 768 < end; e += 1024) {
        uint_t u0 = pairs[e], u1 = pairs[e + 256], u2 = pairs[e + 512], u3 = pairs[e + 768];
        atomicAdd(&cnt64[u0 >> 26], 1);
        atomicAdd(&cnt64[u1 >> 26], 1);
        atomicAdd(&cnt64[u2 >> 26], 1);
        atomicAdd(&cnt64[u3 >> 26], 1);
    }
    for (; e < end; e += 256) atomicAdd(&cnt64[pairs[e] >> 26], 1);
    __syncthreads();
    if (tid < 64) {
        int c = cnt64[tid];
        int v = c;
        #pragma unroll
        for (int off = 1; off < 64; off <<= 1) {
            int u = __shfl_up(v, off, 64);
            if (tid >= off) v += u;
        }
        int excl = start + v - c;
        if (node0 + tid < n) {
            row_start[node0 + tid] = excl;
            dinv[node0 + tid] = rsqrtf((float)(c + 1));  // +1 self loop
        }
        cur[tid] = excl;
    }
    __syncthreads();
    e = start + tid;
    for (; e + 768 < end; e += 1024) {
        uint_t u0 = pairs[e], u1 = pairs[e + 256], u2 = pairs[e + 512], u3 = pairs[e + 768];
        int p0 = atomicAdd(&cur[u0 >> 26], 1);
        int p1 = atomicAdd(&cur[u1 >> 26], 1);
        int p2 = atomicAdd(&cur[u2 >> 26], 1);
        int p3 = atomicAdd(&cur[u3 >> 26], 1);
        csr_src[p0] = (int)(u0 & 0x3FFFFFFu);
        csr_src[p1] = (int)(u1 & 0x3FFFFFFu);
        csr_src[p2] = (int)(u2 & 0x3FFFFFFu);
        csr_src[p3] = (int)(u3 & 0x3FFFFFFu);
    }
    for (; e < end; e += 256) {
        uint_t u = pairs[e];
        int p = atomicAdd(&cur[u >> 26], 1);
        csr_src[p] = (int)(u & 0x3FFFFFFu);
    }
}

// ---------------- W prep: transposed bf16 hi/lo splits ----------------
// w1h/w1l: [128 cols][128 k]; w2h/w2l: [64 cols][128 k]. Wt[c][k] = W[k][c].
__global__ __launch_bounds__(256) void wsplit_kernel(const float* __restrict__ W1,
                                                     const float* __restrict__ W2,
                                                     ushort_t* __restrict__ w1h,
                                                     ushort_t* __restrict__ w1l,
                                                     ushort_t* __restrict__ w2h,
                                                     ushort_t* __restrict__ w2l) {
    int idx = blockIdx.x * 256 + threadIdx.x;
    const int tot1 = 128 * 128;
    const int tot = tot1 + 64 * 128;
    if (idx >= tot) return;
    float v;
    ushort_t* ph;
    ushort_t* pl;
    int o;
    if (idx < tot1) {
        int c = idx >> 7, k = idx & 127;
        v = W1[k * 128 + c];
        ph = w1h; pl = w1l; o = idx;
    } else {
        int j = idx - tot1;
        int c = j >> 7, k = j & 127;
        v = W2[k * 64 + c];
        ph = w2h; pl = w2l; o = j;
    }
    ushort_t h = f32_to_bf16_rn(v);
    float hv = __uint_as_float((uint_t)h << 16);
    ph[o] = h;
    pl[o] = f32_to_bf16_rn(v - hv);
}

// ---------------- MFMA GEMM: Y[n x NCOL] = (X[n x 128] @ W) * rowscale[row] -------
// hi/lo split: F32_IN: 3 terms (xh*wh + xh*wl + xl*wh); bf16 in: 2 terms (exact A).
// B staged in XOR-swizzled LDS (byte ^= (row&7)<<4): conflict-free ds_read_b128,
// no L1 thrash. 4 waves x 32 rows = 128 rows/block; 2 row-tiles/wave for ILP.
// Fragment maps (v_mfma_f32_16x16x32_bf16): A row=lane&15, k=(lane>>4)*8+j;
// B col=lane&15, k=(lane>>4)*8+j; D col=lane&15, row=(lane>>4)*4+reg.
template <int NCOL, bool F32_IN>
__global__ __launch_bounds__(256, 2) void mfma_gemm_kernel(const void* __restrict__ Xv,
                                                           const ushort_t* __restrict__ Wth,
                                                           const ushort_t* __restrict__ Wtl,
                                                           const float* __restrict__ rowscale,
                                                           ushort_t* __restrict__ Y, int n) {
    constexpr int NT = NCOL / 16;          // col tiles (8 or 4)
    constexpr int WB = NCOL * 128 * 2;     // bytes per W array (h or l)
    constexpr int NCH = WB / 16;           // 16B chunks per array
    __shared__ __align__(16) char Bs[2 * WB];   // h @0, l @WB; swizzled

    int tid = threadIdx.x;

    // ---- stage B, swizzled (reg-staged: global_load_lds can't swizzle) ----
    for (int i = tid; i < 2 * NCH; i += 256) {
        bool lo = (i >= NCH);
        int j = lo ? i - NCH : i;
        int row = j >> 4, c = j & 15;        // row = W col index; 16 chunks/row
        bf16x8 v = *(const bf16x8*)((lo ? Wtl : Wth) + row * 128 + c * 8);
        int bo = (row << 8) + (c << 4);
        bo ^= (row & 7) << 4;                // T2 swizzle
        *(bf16x8*)(Bs + (lo ? WB : 0) + bo) = v;
    }
    __syncthreads();

    int wave = tid >> 6;
    int lane = tid & 63;
    int q = lane >> 4;                       // k-quarter selector
    int r16 = lane & 15;                     // A row / B,D col within tile
    int rowBase = blockIdx.x * 128 + wave * 32;
    int ar0 = rowBase + r16;      if (ar0 > n - 1) ar0 = n - 1;
    int ar1 = rowBase + 16 + r16; if (ar1 > n - 1) ar1 = n - 1;

    const float* X = (const float*)Xv;
    const ushort_t* Hb = (const ushort_t*)Xv;

    f32x4 acc[2][NT];
    #pragma unroll
    for (int rt = 0; rt < 2; rt++)
        #pragma unroll
        for (int t = 0; t < NT; t++) acc[rt][t] = (f32x4){0.f, 0.f, 0.f, 0.f};

    #pragma unroll
    for (int ks = 0; ks < 4; ks++) {
        int k0 = ks * 32 + q * 8;            // element index in K
        bf16x8 ah[2], al[2] = {};
        #pragma unroll
        for (int rt = 0; rt < 2; rt++) {
            int arow = rt ? ar1 : ar0;
            if (F32_IN) {
                const float4* xr = (const float4*)(X + (size_t)arow * 128 + k0);
                float4 p0 = xr[0], p1 = xr[1];
                float v[8] = {p0.x, p0.y, p0.z, p0.w, p1.x, p1.y, p1.z, p1.w};
                #pragma unroll
                for (int j = 0; j < 8; j++) {
                    ushort_t hb = f32_to_bf16_rn(v[j]);
                    float hv = __uint_as_float((uint_t)hb << 16);
                    ah[rt][j] = (short)hb;
                    al[rt][j] = (short)f32_to_bf16_rn(v[j] - hv);
                }
            } else {
                ah[rt] = *(const bf16x8*)(Hb + (size_t)arow * 128 + k0);
            }
        }
        #pragma unroll
        for (int t = 0; t < NT; t++) {
            int bo = ((t * 16 + r16) << 8) + ks * 64 + (q << 4);
            bo ^= (r16 & 7) << 4;            // (t*16+r16)&7 == r16&7
            bf16x8 bh = *(const bf16x8*)(Bs + bo);
            bf16x8 bl = *(const bf16x8*)(Bs + WB + bo);
            #pragma unroll
            for (int rt = 0; rt < 2; rt++) {
                acc[rt][t] = __builtin_amdgcn_mfma_f32_16x16x32_bf16(ah[rt], bh, acc[rt][t], 0, 0, 0);
                acc[rt][t] = __builtin_amdgcn_mfma_f32_16x16x32_bf16(ah[rt], bl, acc[rt][t], 0, 0, 0);
                if (F32_IN)
                    acc[rt][t] = __builtin_amdgcn_mfma_f32_16x16x32_bf16(al[rt], bh, acc[rt][t], 0, 0, 0);
            }
        }
    }

    #pragma unroll
    for (int rt = 0; rt < 2; rt++) {
        #pragma unroll
        for (int rr = 0; rr < 4; rr++) {
            int row = rowBase + rt * 16 + q * 4 + rr;
            if (row < n) {
                float rs = rowscale[row];
                #pragma unroll
                for (int t = 0; t < NT; t++)
                    Y[(size_t)row * NCOL + t * 16 + r16] = f32_to_bf16_rn(acc[rt][t][rr] * rs);
            }
        }
    }
}

// ---------------- aggregation layer 1, channel-half pass ----------------
// Pass HALF gathers ONLY 128B line HALF of each xw row (working set 12.8 MB).
// Lane (g = lane>>3, cb = lane&7): channels HALF*64 + cb*8 .. +8.
// Two chains x 8 groups = 16 edges/iter; masked clamped tail.
// Stores h PRE-norm (bf16) + per-pass sum-of-squares partial ssOut[i].
template <int HALF>
__global__ __launch_bounds__(256) void agg1h_kernel(const ushort_t* __restrict__ xw,
                                                    const int* __restrict__ csr_src,
                                                    const int* __restrict__ row_start,
                                                    const float* __restrict__ dinv,
                                                    const float* __restrict__ b1,
                                                    ushort_t* __restrict__ h,
                                                    float* __restrict__ ssOut, int n) {
    int wid = (blockIdx.x * 256 + threadIdx.x) >> 6;
    int lane = threadIdx.x & 63;
    if (wid >= n) return;
    int i = wid;
    int g = lane >> 3;                       // 8 edge groups
    int cb = lane & 7;                       // 8 x 16B chunks = this 128B half
    const uint4* X4 = (const uint4*)xw;      // row i half = X4[i*16 + HALF*8 + cb]
    int hoff = HALF * 8 + cb;
    float di = dinv[i];
    int e0 = row_start[i], e1 = row_start[i + 1];

    f32v2 a0 = {0.f, 0.f}, a1 = {0.f, 0.f}, a2 = {0.f, 0.f}, a3 = {0.f, 0.f};
    // self row: group 0 contributes once
    {
        uint4 v = X4[(size_t)i * 16 + hoff];
        acc_row_c(a0, a1, a2, a3, v, (g == 0) ? 1.0f : 0.0f);
    }
    int e = e0;
    // main: 16 edges/iter, 2 independent idx->gather chains x 8 groups
    for (; e + 16 <= e1; e += 16) {
        int s0 = csr_src[e + g];
        int s1 = csr_src[e + 8 + g];
        uint4 v0 = X4[(size_t)s0 * 16 + hoff];
        uint4 v1 = X4[(size_t)s1 * 16 + hoff];
        acc_row(a0, a1, a2, a3, v0);
        acc_row(a0, a1, a2, a3, v1);
    }
    // masked tail, positions clamped to last (dups are L1-hot, coef 0)
    if (e < e1) {
        int last = e1 - 1;
        int p0 = e + g, p1 = e + 8 + g;
        int s0 = csr_src[p0 <= last ? p0 : last];
        int s1 = csr_src[p1 <= last ? p1 : last];
        uint4 v0 = X4[(size_t)s0 * 16 + hoff];
        uint4 v1 = X4[(size_t)s1 * 16 + hoff];
        acc_row_c(a0, a1, a2, a3, v0, (p0 <= last) ? 1.0f : 0.0f);
        acc_row_c(a0, a1, a2, a3, v1, (p1 <= last) ? 1.0f : 0.0f);
    }
    // combine the 8 edge-groups (after this every lane holds finals for its cb)
    #pragma unroll
    for (int m = 8; m <= 32; m <<= 1) {
        a0.x += __shfl_xor(a0.x, m, 64); a0.y += __shfl_xor(a0.y, m, 64);
        a1.x += __shfl_xor(a1.x, m, 64); a1.y += __shfl_xor(a1.y, m, 64);
        a2.x += __shfl_xor(a2.x, m, 64); a2.y += __shfl_xor(a2.y, m, 64);
        a3.x += __shfl_xor(a3.x, m, 64); a3.y += __shfl_xor(a3.y, m, 64);
    }
    // bias + relu for channels HALF*64 + cb*8 .. +8 (pre-norm values)
    const float2* bp = (const float2*)(b1 + HALF * 64 + cb * 8);
    float2 b0v = bp[0], b1v = bp[1], b2v = bp[2], b3v = bp[3];
    float vals[8];
    vals[0] = fmaxf(fmaf(a0.x, di, b0v.x), 0.f);
    vals[1] = fmaxf(fmaf(a0.y, di, b0v.y), 0.f);
    vals[2] = fmaxf(fmaf(a1.x, di, b1v.x), 0.f);
    vals[3] = fmaxf(fmaf(a1.y, di, b1v.y), 0.f);
    vals[4] = fmaxf(fmaf(a2.x, di, b2v.x), 0.f);
    vals[5] = fmaxf(fmaf(a2.y, di, b2v.y), 0.f);
    vals[6] = fmaxf(fmaf(a3.x, di, b3v.x), 0.f);
    vals[7] = fmaxf(fmaf(a3.y, di, b3v.y), 0.f);
    float ss = 0.f;
    #pragma unroll
    for (int j = 0; j < 8; j++) ss = fmaf(vals[j], vals[j], ss);
    #pragma unroll
    for (int m = 1; m <= 4; m <<= 1) ss += __shfl_xor(ss, m, 64);
    if (lane == 0) ssOut[i] = ss;            // half's total sum of squares
    if (g == 0) {
        uint4 o;
        o.x = (uint_t)f32_to_bf16_rn(vals[0]) | ((uint_t)f32_to_bf16_rn(vals[1]) << 16);
        o.y = (uint_t)f32_to_bf16_rn(vals[2]) | ((uint_t)f32_to_bf16_rn(vals[3]) << 16);
        o.z = (uint_t)f32_to_bf16_rn(vals[4]) | ((uint_t)f32_to_bf16_rn(vals[5]) << 16);
        o.w = (uint_t)f32_to_bf16_rn(vals[6]) | ((uint_t)f32_to_bf16_rn(vals[7]) << 16);
        ((uint4*)h)[(size_t)i * 16 + hoff] = o;
    }
}

// ---------------- rowscale2 = dinv / max(sqrt(ssA+ssB), 1e-12) ----------------
__global__ __launch_bounds__(256) void nrm_kernel(const float* __restrict__ ssA,
                                                  const float* __restrict__ ssB,
                                                  const float* __restrict__ dinv,
                                                  float* __restrict__ rowscale2, int n) {
    int i = blockIdx.x * 256 + threadIdx.x;
    if (i < n) {
        float norm = sqrtf(ssA[i] + ssB[i]);
        rowscale2[i] = dinv[i] / fmaxf(norm, 1e-12f);
    }
}

// ---------------- aggregation layer 2: pull + bias -> d_out (f32) ----------------
// hw rows pre-scaled by dinv[i]*normscale[i] (folded in gemm2 epilogue);
// result = dinv[i]*(self + sum) + b2. (R10-measured version.)
__global__ __launch_bounds__(256) void agg2_kernel(const ushort_t* __restrict__ hw,
                                                   const int* __restrict__ csr_src,
                                                   const int* __restrict__ row_start,
                                                   const float* __restrict__ dinv,
                                                   const float* __restrict__ b2,
                                                   float* __restrict__ out, int n) {
    int wid = (blockIdx.x * 256 + threadIdx.x) >> 6;
    int lane = threadIdx.x & 63;
    int i = wid * 2 + (lane >> 5);
    int l = lane & 31;
    if (i >= n) return;
    float di = dinv[i];
    uint_t su = ((const uint_t*)(hw + (size_t)i * OUT_CH))[l];
    float ax = bf16lo_to_f32(su), ay = bf16hi_to_f32(su);
    int e0 = row_start[i], e1 = row_start[i + 1];
    int e = e0;
    for (; e + 8 <= e1; e += 8) {
        int s[8];
        #pragma unroll
        for (int j = 0; j < 8; j++) s[j] = csr_src[e + j];
        uint_t v[8];
        #pragma unroll
        for (int j = 0; j < 8; j++)
            v[j] = ((const uint_t*)(hw + (size_t)s[j] * OUT_CH))[l];
        #pragma unroll
        for (int j = 0; j < 8; j++) {
            ax += bf16lo_to_f32(v[j]);
            ay += bf16hi_to_f32(v[j]);
        }
    }
    if (e < e1) {
        int last = e1 - 1;
        int s[8];
        #pragma unroll
        for (int j = 0; j < 8; j++) {
            int idx = e + j;
            s[j] = csr_src[idx <= last ? idx : last];
        }
        uint_t v[8];
        #pragma unroll
        for (int j = 0; j < 8; j++)
            v[j] = ((const uint_t*)(hw + (size_t)s[j] * OUT_CH))[l];
        #pragma unroll
        for (int j = 0; j < 8; j++) {
            float c = (e + j <= last) ? 1.0f : 0.0f;
            ax = fmaf(bf16lo_to_f32(v[j]), c, ax);
            ay = fmaf(bf16hi_to_f32(v[j]), c, ay);
        }
    }
    ax = fmaf(ax, di, b2[l * 2]);
    ay = fmaf(ay, di, b2[l * 2 + 1]);
    ((float2*)(out + (size_t)i * OUT_CH))[l] = make_float2(ax, ay);
}

extern "C" void kernel_launch(void* const* d_in, const int* in_sizes, int n_in,
                              void* d_out, int out_size, void* d_ws, size_t ws_size,
                              hipStream_t stream) {
    const float* x  = (const float*)d_in[0];
    const int*   ei = (const int*)d_in[1];
    const float* W1 = (const float*)d_in[2];
    const float* b1 = (const float*)d_in[3];
    const float* W2 = (const float*)d_in[4];
    const float* b2 = (const float*)d_in[5];
    float* out = (float*)d_out;

    const int N = in_sizes[0] / IN_CH;     // 100000
    const int E = in_sizes[1] / 2;         // 1600000
    const int* src = ei;
    const int* dst = ei + E;
    const int NB = (N + 63) / 64;          // buckets (1563)
    const int chunk = (E + NBLK - 1) / NBLK;

    // ---- workspace carve ----
    char* base = (char*)d_ws;
    size_t off = 0;
    auto alloc = [&](size_t bytes) -> void* {
        void* p = base + off;
        off = (off + bytes + 255) & ~(size_t)255;
        return p;
    };
    int*      blk_cnt     = (int*)alloc((size_t)NBLK * NB * 4);
    int*      blk_start   = (int*)alloc((size_t)NBLK * NB * 4);
    int*      btot        = (int*)alloc((size_t)NB * 4);
    int*      bucket_base = (int*)alloc((size_t)(NB + 1) * 4);
    int*      row_start   = (int*)alloc((size_t)(N + 1) * 4);
    float*    dinv        = (float*)alloc((size_t)N * 4);
    int*      csr_src     = (int*)alloc((size_t)E * 4);
    uint_t*   pairs       = (uint_t*)alloc((size_t)E * 4);
    ushort_t* xw          = (ushort_t*)alloc((size_t)N * HID * 2);
    ushort_t* h           = (ushort_t*)alloc((size_t)N * HID * 2);
    ushort_t* hw          = (ushort_t*)alloc((size_t)N * OUT_CH * 2);
    ushort_t* w1h         = (ushort_t*)alloc((size_t)128 * 128 * 2);
    ushort_t* w1l         = (ushort_t*)alloc((size_t)128 * 128 * 2);
    ushort_t* w2h         = (ushort_t*)alloc((size_t)64 * 128 * 2);
    ushort_t* w2l         = (ushort_t*)alloc((size_t)64 * 128 * 2);
    float*    ssA         = (float*)alloc((size_t)N * 4);
    float*    ssB         = (float*)alloc((size_t)N * 4);
    float*    rowscale2   = (float*)alloc((size_t)N * 4);
    (void)ws_size;

    // W splits (tiny)
    wsplit_kernel<<<(128 * 128 + 64 * 128 + 255) / 256, 256, 0, stream>>>(
        W1, W2, w1h, w1l, w2h, w2l);

    // CSR build -- no global atomics anywhere
    hist_kernel<<<NBLK, 256, 0, stream>>>(dst, E, chunk, NB, blk_cnt);
    btot_kernel<<<(NB + 255) / 256, 256, 0, stream>>>(blk_cnt, NB, btot);
    scan_kernel<<<1, 256, 0, stream>>>(btot, NB, bucket_base, row_start, N, E);
    colscan_kernel<<<(NB + 15) / 16, 256, 0, stream>>>(blk_cnt, bucket_base, NB, blk_start);
    scatter_kernel<<<NBLK, 256, 0, stream>>>(src, dst, E, chunk, NB, blk_start, pairs);
    fine_fill_kernel<<<NB, 256, 0, stream>>>(pairs, bucket_base, row_start, dinv,
                                             csr_src, N);

    // layer 1 (MFMA, 3-term hi/lo split; xw pre-scaled by dinv[row])
    mfma_gemm_kernel<128, true><<<(N + 127) / 128, 256, 0, stream>>>(
        x, w1h, w1l, dinv, xw, N);
    // agg1 in two sequential channel-half passes (12.8 MB working set each);
    // h stored PRE-norm, norm folded into gemm2 rowscale.
    int aggGrid = (N * 64 + 255) / 256;
    agg1h_kernel<0><<<aggGrid, 256, 0, stream>>>(xw, csr_src, row_start, dinv, b1,
                                                 h, ssA, N);
    agg1h_kernel<1><<<aggGrid, 256, 0, stream>>>(xw, csr_src, row_start, dinv, b1,
                                                 h, ssB, N);
    nrm_kernel<<<(N + 255) / 256, 256, 0, stream>>>(ssA, ssB, dinv, rowscale2, N);
    // layer 2 (MFMA, 2-term; hw = rowscale2[row] * (h_pre @ W2))
    mfma_gemm_kernel<64, false><<<(N + 127) / 128, 256, 0, stream>>>(
        h, w2h, w2l, rowscale2, hw, N);
    int waves2 = (N + 1) / 2;
    agg2_kernel<<<(waves2 * 64 + 255) / 256, 256, 0, stream>>>(hw, csr_src, row_start,
                                                               dinv, b2, out, N);
}

// Round 9
// 306.917 us; speedup vs baseline: 1.0422x; 1.0422x over previous
//
#include <hip/hip_runtime.h>
#include <hip/hip_bf16.h>

// GCN encoder: 2x GCNConv, symmetric norm, relu + L2 rownorm between.
// Pull aggregation over CSR-by-dst, bf16 intermediates (f32 accumulate).
// R7: CSR built with ZERO global atomics (LDS histograms + scans).
// R8: agg loops fully batched; dinv[src] folded into GEMM epilogue.
// R9: GEMMs on MFMA 16x16x32 bf16, hi/lo split (f32-equiv accuracy).
// R10: B staged in XOR-swizzled LDS; 2 row-tiles/wave. GEMMs off the radar.
// R11: agg1 16B/lane gather: NEUTRAL => not VALU-bound.
// R12: 4 gather chains: +5% => ~3.5 TB/s L2-miss-path ceiling (latency AND
//      issue-rate ruled out).
// R13: channel-half split REGRESSED (2x44 vs 62 us; FETCH 190->173 only):
//      misses are compulsory random-line traffic; working-set halving is not
//      a lever. agg1 declared at its structural floor (~62 us).
// R14 (this round): agg1 reverted to R12 (best measured). agg2 ported to the
// same proven structure: 1 node/wave, 16B/lane x 8 chunk-lanes covering the
// 128B hw row, 8 edge-groups x 4 independent gather chains, masked clamped
// 32-position tail. Math identical; only f32 add order changes.

#define IN_CH 128
#define HID 128
#define OUT_CH 64
#define NBLK 128          // chunk blocks for hist/scatter
#define MAXNB 1568        // >= ceil(100000/64)=1563 buckets

typedef unsigned int uint_t;
typedef unsigned short ushort_t;
typedef __attribute__((ext_vector_type(8))) short bf16x8;
typedef __attribute__((ext_vector_type(4))) float f32x4;
typedef __attribute__((ext_vector_type(2))) float f32v2;

__device__ __forceinline__ ushort_t f32_to_bf16_rn(float f) {
    uint_t u = __float_as_uint(f);
    u = (u + 0x7fffu + ((u >> 16) & 1u)) >> 16;
    return (ushort_t)u;
}
__device__ __forceinline__ float bf16lo_to_f32(uint_t u) { return __uint_as_float(u << 16); }
__device__ __forceinline__ float bf16hi_to_f32(uint_t u) { return __uint_as_float(u & 0xffff0000u); }

// accumulate one 16B row-chunk (8 bf16 channels) into 4 f32v2 accumulators
__device__ __forceinline__ void acc_row(f32v2& a0, f32v2& a1, f32v2& a2, f32v2& a3,
                                        uint4 v) {
    a0 += (f32v2){bf16lo_to_f32(v.x), bf16hi_to_f32(v.x)};
    a1 += (f32v2){bf16lo_to_f32(v.y), bf16hi_to_f32(v.y)};
    a2 += (f32v2){bf16lo_to_f32(v.z), bf16hi_to_f32(v.z)};
    a3 += (f32v2){bf16lo_to_f32(v.w), bf16hi_to_f32(v.w)};
}
__device__ __forceinline__ void acc_row_c(f32v2& a0, f32v2& a1, f32v2& a2, f32v2& a3,
                                          uint4 v, float c) {
    f32v2 cv = {c, c};
    a0 += (f32v2){bf16lo_to_f32(v.x), bf16hi_to_f32(v.x)} * cv;
    a1 += (f32v2){bf16lo_to_f32(v.y), bf16hi_to_f32(v.y)} * cv;
    a2 += (f32v2){bf16lo_to_f32(v.z), bf16hi_to_f32(v.z)} * cv;
    a3 += (f32v2){bf16lo_to_f32(v.w), bf16hi_to_f32(v.w)} * cv;
}

// ---------------- phase 1: per-block LDS bucket histogram ----------------
__global__ __launch_bounds__(256) void hist_kernel(const int* __restrict__ dst, int E,
                                                   int chunk, int NB,
                                                   int* __restrict__ blk_cnt) {
    __shared__ int hist[MAXNB];
    int tid = threadIdx.x;
    int blk = blockIdx.x;
    for (int b = tid; b < NB; b += 256) hist[b] = 0;
    __syncthreads();
    int start = blk * chunk;
    int end = start + chunk; if (end > E) end = E;
    int e = start + tid;
    for (; e + 768 < end; e += 1024) {
        int d0 = dst[e], d1 = dst[e + 256], d2 = dst[e + 512], d3 = dst[e + 768];
        atomicAdd(&hist[d0 >> 6], 1);
        atomicAdd(&hist[d1 >> 6], 1);
        atomicAdd(&hist[d2 >> 6], 1);
        atomicAdd(&hist[d3 >> 6], 1);
    }
    for (; e < end; e += 256) atomicAdd(&hist[dst[e] >> 6], 1);
    __syncthreads();
    for (int b = tid; b < NB; b += 256) blk_cnt[blk * NB + b] = hist[b];
}

// ---------------- phase 2a: bucket totals (column sums) ----------------
__global__ __launch_bounds__(256) void btot_kernel(const int* __restrict__ blk_cnt,
                                                   int NB, int* __restrict__ btot) {
    int b = blockIdx.x * 256 + threadIdx.x;
    if (b < NB) {
        int sum = 0;
        #pragma unroll 8
        for (int blk = 0; blk < NBLK; blk++) sum += blk_cnt[blk * NB + b];
        btot[b] = sum;
    }
}

// ---------------- phase 2b: single-block exclusive scan over buckets --------------
__global__ __launch_bounds__(256) void scan_kernel(const int* __restrict__ btot, int NB,
                                                   int* __restrict__ bucket_base,
                                                   int* __restrict__ row_start,
                                                   int n, int E) {
    __shared__ int sdata[256];
    __shared__ int carryS;
    int tid = threadIdx.x;
    if (tid == 0) carryS = 0;
    __syncthreads();
    int nchunks = (NB + 255) / 256;
    for (int c = 0; c < nchunks; c++) {
        int i = c * 256 + tid;
        int v = (i < NB) ? btot[i] : 0;
        sdata[tid] = v;
        __syncthreads();
        for (int off = 1; off < 256; off <<= 1) {
            int t = (tid >= off) ? sdata[tid - off] : 0;
            __syncthreads();
            sdata[tid] += t;
            __syncthreads();
        }
        if (i < NB) bucket_base[i] = carryS + sdata[tid] - v;
        __syncthreads();
        if (tid == 0) carryS += sdata[255];
        __syncthreads();
    }
    if (tid == 0) {
        bucket_base[NB] = E;
        row_start[n] = E;
    }
}

// ---------------- phase 2c: per-bucket exclusive scan over blocks -----------------
__global__ __launch_bounds__(256) void colscan_kernel(const int* __restrict__ blk_cnt,
                                                      const int* __restrict__ bucket_base,
                                                      int NB, int* __restrict__ blk_start) {
    __shared__ int tile[NBLK][16];
    int tid = threadIdx.x;
    int b0 = blockIdx.x * 16;
    for (int idx = tid; idx < NBLK * 16; idx += 256) {
        int blk = idx >> 4, b = idx & 15;
        if (b0 + b < NB) tile[blk][b] = blk_cnt[blk * NB + b0 + b];
    }
    __syncthreads();
    if (tid < 16 && b0 + tid < NB) {
        int running = bucket_base[b0 + tid];
        for (int blk = 0; blk < NBLK; blk++) {
            int t = tile[blk][tid];
            tile[blk][tid] = running;
            running += t;
        }
    }
    __syncthreads();
    for (int idx = tid; idx < NBLK * 16; idx += 256) {
        int blk = idx >> 4, b = idx & 15;
        if (b0 + b < NB) blk_start[blk * NB + b0 + b] = tile[blk][b];
    }
}

// ---------------- phase 3: scatter, LDS tickets only ----------------
// pack: src (26 bits) | (dst & 63) << 26.
__global__ __launch_bounds__(256) void scatter_kernel(const int* __restrict__ src,
                                                      const int* __restrict__ dst,
                                                      int E, int chunk, int NB,
                                                      const int* __restrict__ blk_start,
                                                      uint_t* __restrict__ pairs) {
    __shared__ int cur[MAXNB];
    int tid = threadIdx.x;
    int blk = blockIdx.x;
    for (int b = tid; b < NB; b += 256) cur[b] = blk_start[blk * NB + b];
    __syncthreads();
    int start = blk * chunk;
    int end = start + chunk; if (end > E) end = E;
    int e = start + tid;
    for (; e + 768 < end; e += 1024) {
        int d0 = dst[e], d1 = dst[e + 256], d2 = dst[e + 512], d3 = dst[e + 768];
        int s0 = src[e], s1 = src[e + 256], s2 = src[e + 512], s3 = src[e + 768];
        int p0 = atomicAdd(&cur[d0 >> 6], 1);
        int p1 = atomicAdd(&cur[d1 >> 6], 1);
        int p2 = atomicAdd(&cur[d2 >> 6], 1);
        int p3 = atomicAdd(&cur[d3 >> 6], 1);
        pairs[p0] = (uint_t)s0 | ((uint_t)(d0 & 63) << 26);
        pairs[p1] = (uint_t)s1 | ((uint_t)(d1 & 63) << 26);
        pairs[p2] = (uint_t)s2 | ((uint_t)(d2 & 63) << 26);
        pairs[p3] = (uint_t)s3 | ((uint_t)(d3 & 63) << 26);
    }
    for (; e < end; e += 256) {
        int d = dst[e], s = src[e];
        int p = atomicAdd(&cur[d >> 6], 1);
        pairs[p] = (uint_t)s | ((uint_t)(d & 63) << 26);
    }
}

// ---------------- phase 4: fine fill -- per bucket: counts, row_start, dinv, csr ---
__global__ __launch_bounds__(256) void fine_fill_kernel(const uint_t* __restrict__ pairs,
                                                        const int* __restrict__ bucket_base,
                                                        int* __restrict__ row_start,
                                                        float* __restrict__ dinv,
                                                        int* __restrict__ csr_src,
                                                        int n) {
    __shared__ int cnt64[64];
    __shared__ int cur[64];
    int b = blockIdx.x;
    int node0 = b << 6;
    int tid = threadIdx.x;
    if (tid < 64) cnt64[tid] = 0;
    __syncthreads();
    int start = bucket_base[b];
    int end = bucket_base[b + 1];
    int e = start + tid;
    for (; e + 768 < end; e += 1024) {
        uint_t u0 = pairs[e], u1 = pairs[e + 256], u2 = pairs[e + 512], u3 = pairs[e + 768];
        atomicAdd(&cnt64[u0 >> 26], 1);
        atomicAdd(&cnt64[u1 >> 26], 1);
        atomicAdd(&cnt64[u2 >> 26], 1);
        atomicAdd(&cnt64[u3 >> 26], 1);
    }
    for (; e < end; e += 256) atomicAdd(&cnt64[pairs[e] >> 26], 1);
    __syncthreads();
    if (tid < 64) {
        int c = cnt64[tid];
        int v = c;
        #pragma unroll
        for (int off = 1; off < 64; off <<= 1) {
            int u = __shfl_up(v, off, 64);
            if (tid >= off) v += u;
        }
        int excl = start + v - c;
        if (node0 + tid < n) {
            row_start[node0 + tid] = excl;
            dinv[node0 + tid] = rsqrtf((float)(c + 1));  // +1 self loop
        }
        cur[tid] = excl;
    }
    __syncthreads();
    e = start + tid;
    for (; e + 768 < end; e += 1024) {
        uint_t u0 = pairs[e], u1 = pairs[e + 256], u2 = pairs[e + 512], u3 = pairs[e + 768];
        int p0 = atomicAdd(&cur[u0 >> 26], 1);
        int p1 = atomicAdd(&cur[u1 >> 26], 1);
        int p2 = atomicAdd(&cur[u2 >> 26], 1);
        int p3 = atomicAdd(&cur[u3 >> 26], 1);
        csr_src[p0] = (int)(u0 & 0x3FFFFFFu);
        csr_src[p1] = (int)(u1 & 0x3FFFFFFu);
        csr_src[p2] = (int)(u2 & 0x3FFFFFFu);
        csr_src[p3] = (int)(u3 & 0x3FFFFFFu);
    }
    for (; e < end; e += 256) {
        uint_t u = pairs[e];
        int p = atomicAdd(&cur[u >> 26], 1);
        csr_src[p] = (int)(u & 0x3FFFFFFu);
    }
}

// ---------------- W prep: transposed bf16 hi/lo splits ----------------
// w1h/w1l: [128 cols][128 k]; w2h/w2l: [64 cols][128 k]. Wt[c][k] = W[k][c].
__global__ __launch_bounds__(256) void wsplit_kernel(const float* __restrict__ W1,
                                                     const float* __restrict__ W2,
                                                     ushort_t* __restrict__ w1h,
                                                     ushort_t* __restrict__ w1l,
                                                     ushort_t* __restrict__ w2h,
                                                     ushort_t* __restrict__ w2l) {
    int idx = blockIdx.x * 256 + threadIdx.x;
    const int tot1 = 128 * 128;
    const int tot = tot1 + 64 * 128;
    if (idx >= tot) return;
    float v;
    ushort_t* ph;
    ushort_t* pl;
    int o;
    if (idx < tot1) {
        int c = idx >> 7, k = idx & 127;
        v = W1[k * 128 + c];
        ph = w1h; pl = w1l; o = idx;
    } else {
        int j = idx - tot1;
        int c = j >> 7, k = j & 127;
        v = W2[k * 64 + c];
        ph = w2h; pl = w2l; o = j;
    }
    ushort_t h = f32_to_bf16_rn(v);
    float hv = __uint_as_float((uint_t)h << 16);
    ph[o] = h;
    pl[o] = f32_to_bf16_rn(v - hv);
}

// ---------------- MFMA GEMM: Y[n x NCOL] = (X[n x 128] @ W) * rowscale[row] -------
// hi/lo split: F32_IN: 3 terms (xh*wh + xh*wl + xl*wh); bf16 in: 2 terms (exact A).
// B staged in XOR-swizzled LDS (byte ^= (row&7)<<4): conflict-free ds_read_b128,
// no L1 thrash. 4 waves x 32 rows = 128 rows/block; 2 row-tiles/wave for ILP.
// Fragment maps (v_mfma_f32_16x16x32_bf16): A row=lane&15, k=(lane>>4)*8+j;
// B col=lane&15, k=(lane>>4)*8+j; D col=lane&15, row=(lane>>4)*4+reg.
template <int NCOL, bool F32_IN>
__global__ __launch_bounds__(256, 2) void mfma_gemm_kernel(const void* __restrict__ Xv,
                                                           const ushort_t* __restrict__ Wth,
                                                           const ushort_t* __restrict__ Wtl,
                                                           const float* __restrict__ rowscale,
                                                           ushort_t* __restrict__ Y, int n) {
    constexpr int NT = NCOL / 16;          // col tiles (8 or 4)
    constexpr int WB = NCOL * 128 * 2;     // bytes per W array (h or l)
    constexpr int NCH = WB / 16;           // 16B chunks per array
    __shared__ __align__(16) char Bs[2 * WB];   // h @0, l @WB; swizzled

    int tid = threadIdx.x;

    // ---- stage B, swizzled (reg-staged: global_load_lds can't swizzle) ----
    for (int i = tid; i < 2 * NCH; i += 256) {
        bool lo = (i >= NCH);
        int j = lo ? i - NCH : i;
        int row = j >> 4, c = j & 15;        // row = W col index; 16 chunks/row
        bf16x8 v = *(const bf16x8*)((lo ? Wtl : Wth) + row * 128 + c * 8);
        int bo = (row << 8) + (c << 4);
        bo ^= (row & 7) << 4;                // T2 swizzle
        *(bf16x8*)(Bs + (lo ? WB : 0) + bo) = v;
    }
    __syncthreads();

    int wave = tid >> 6;
    int lane = tid & 63;
    int q = lane >> 4;                       // k-quarter selector
    int r16 = lane & 15;                     // A row / B,D col within tile
    int rowBase = blockIdx.x * 128 + wave * 32;
    int ar0 = rowBase + r16;      if (ar0 > n - 1) ar0 = n - 1;
    int ar1 = rowBase + 16 + r16; if (ar1 > n - 1) ar1 = n - 1;

    const float* X = (const float*)Xv;
    const ushort_t* Hb = (const ushort_t*)Xv;

    f32x4 acc[2][NT];
    #pragma unroll
    for (int rt = 0; rt < 2; rt++)
        #pragma unroll
        for (int t = 0; t < NT; t++) acc[rt][t] = (f32x4){0.f, 0.f, 0.f, 0.f};

    #pragma unroll
    for (int ks = 0; ks < 4; ks++) {
        int k0 = ks * 32 + q * 8;            // element index in K
        bf16x8 ah[2], al[2] = {};
        #pragma unroll
        for (int rt = 0; rt < 2; rt++) {
            int arow = rt ? ar1 : ar0;
            if (F32_IN) {
                const float4* xr = (const float4*)(X + (size_t)arow * 128 + k0);
                float4 p0 = xr[0], p1 = xr[1];
                float v[8] = {p0.x, p0.y, p0.z, p0.w, p1.x, p1.y, p1.z, p1.w};
                #pragma unroll
                for (int j = 0; j < 8; j++) {
                    ushort_t hb = f32_to_bf16_rn(v[j]);
                    float hv = __uint_as_float((uint_t)hb << 16);
                    ah[rt][j] = (short)hb;
                    al[rt][j] = (short)f32_to_bf16_rn(v[j] - hv);
                }
            } else {
                ah[rt] = *(const bf16x8*)(Hb + (size_t)arow * 128 + k0);
            }
        }
        #pragma unroll
        for (int t = 0; t < NT; t++) {
            int bo = ((t * 16 + r16) << 8) + ks * 64 + (q << 4);
            bo ^= (r16 & 7) << 4;            // (t*16+r16)&7 == r16&7
            bf16x8 bh = *(const bf16x8*)(Bs + bo);
            bf16x8 bl = *(const bf16x8*)(Bs + WB + bo);
            #pragma unroll
            for (int rt = 0; rt < 2; rt++) {
                acc[rt][t] = __builtin_amdgcn_mfma_f32_16x16x32_bf16(ah[rt], bh, acc[rt][t], 0, 0, 0);
                acc[rt][t] = __builtin_amdgcn_mfma_f32_16x16x32_bf16(ah[rt], bl, acc[rt][t], 0, 0, 0);
                if (F32_IN)
                    acc[rt][t] = __builtin_amdgcn_mfma_f32_16x16x32_bf16(al[rt], bh, acc[rt][t], 0, 0, 0);
            }
        }
    }

    #pragma unroll
    for (int rt = 0; rt < 2; rt++) {
        #pragma unroll
        for (int rr = 0; rr < 4; rr++) {
            int row = rowBase + rt * 16 + q * 4 + rr;
            if (row < n) {
                float rs = rowscale[row];
                #pragma unroll
                for (int t = 0; t < NT; t++)
                    Y[(size_t)row * NCOL + t * 16 + r16] = f32_to_bf16_rn(acc[rt][t][rr] * rs);
            }
        }
    }
}

// ---------------- aggregation layer 1: pull + bias + relu + L2 rownorm ----------------
// xw rows pre-scaled by dinv[src]; result = dinv[i]*(self + sum) + b1.
// 16B/lane gather (16 lanes cover a 256B row) with FOUR independent gather
// chains per wave: chain j, group g owns edge position e + 4j + g.
// Masked position-clamped 16-edge tail (clamped dups are L1-hot, coef 0).
__global__ __launch_bounds__(256) void agg1_kernel(const ushort_t* __restrict__ xw,
                                                   const int* __restrict__ csr_src,
                                                   const int* __restrict__ row_start,
                                                   const float* __restrict__ dinv,
                                                   const float* __restrict__ b1,
                                                   ushort_t* __restrict__ h, int n) {
    int wid = (blockIdx.x * 256 + threadIdx.x) >> 6;
    int lane = threadIdx.x & 63;
    if (wid >= n) return;
    int i = wid;
    int g = lane >> 4;
    int cb = lane & 15;
    const uint4* X4 = (const uint4*)xw;      // row i = X4[i*16 + cb]
    float di = dinv[i];
    int e0 = row_start[i], e1 = row_start[i + 1];

    f32v2 a0 = {0.f, 0.f}, a1 = {0.f, 0.f}, a2 = {0.f, 0.f}, a3 = {0.f, 0.f};
    // self row: group 0 contributes once
    {
        uint4 v = X4[(size_t)i * 16 + cb];
        acc_row_c(a0, a1, a2, a3, v, (g == 0) ? 1.0f : 0.0f);
    }
    int e = e0;
    // main loop: 16 edges/iter, 4 independent idx->gather chains in flight
    for (; e + 16 <= e1; e += 16) {
        int s0 = csr_src[e + g];
        int s1 = csr_src[e + 4 + g];
        int s2 = csr_src[e + 8 + g];
        int s3 = csr_src[e + 12 + g];
        uint4 v0 = X4[(size_t)s0 * 16 + cb];
        uint4 v1 = X4[(size_t)s1 * 16 + cb];
        uint4 v2 = X4[(size_t)s2 * 16 + cb];
        uint4 v3 = X4[(size_t)s3 * 16 + cb];
        acc_row(a0, a1, a2, a3, v0);
        acc_row(a0, a1, a2, a3, v1);
        acc_row(a0, a1, a2, a3, v2);
        acc_row(a0, a1, a2, a3, v3);
    }
    // masked tail: same 4-chain layout, positions clamped to last
    if (e < e1) {
        int last = e1 - 1;
        int p0 = e + g, p1 = e + 4 + g, p2 = e + 8 + g, p3 = e + 12 + g;
        int s0 = csr_src[p0 <= last ? p0 : last];
        int s1 = csr_src[p1 <= last ? p1 : last];
        int s2 = csr_src[p2 <= last ? p2 : last];
        int s3 = csr_src[p3 <= last ? p3 : last];
        uint4 v0 = X4[(size_t)s0 * 16 + cb];
        uint4 v1 = X4[(size_t)s1 * 16 + cb];
        uint4 v2 = X4[(size_t)s2 * 16 + cb];
        uint4 v3 = X4[(size_t)s3 * 16 + cb];
        acc_row_c(a0, a1, a2, a3, v0, (p0 <= last) ? 1.0f : 0.0f);
        acc_row_c(a0, a1, a2, a3, v1, (p1 <= last) ? 1.0f : 0.0f);
        acc_row_c(a0, a1, a2, a3, v2, (p2 <= last) ? 1.0f : 0.0f);
        acc_row_c(a0, a1, a2, a3, v3, (p3 <= last) ? 1.0f : 0.0f);
    }
    // combine the 4 edge-groups
    #pragma unroll
    for (int m = 16; m <= 32; m <<= 1) {
        a0.x += __shfl_xor(a0.x, m, 64); a0.y += __shfl_xor(a0.y, m, 64);
        a1.x += __shfl_xor(a1.x, m, 64); a1.y += __shfl_xor(a1.y, m, 64);
        a2.x += __shfl_xor(a2.x, m, 64); a2.y += __shfl_xor(a2.y, m, 64);
        a3.x += __shfl_xor(a3.x, m, 64); a3.y += __shfl_xor(a3.y, m, 64);
    }
    // bias + relu for channels cb*8 .. cb*8+7
    const float2* bp = (const float2*)(b1 + cb * 8);
    float2 b0v = bp[0], b1v = bp[1], b2v = bp[2], b3v = bp[3];
    float vals[8];
    vals[0] = fmaxf(fmaf(a0.x, di, b0v.x), 0.f);
    vals[1] = fmaxf(fmaf(a0.y, di, b0v.y), 0.f);
    vals[2] = fmaxf(fmaf(a1.x, di, b1v.x), 0.f);
    vals[3] = fmaxf(fmaf(a1.y, di, b1v.y), 0.f);
    vals[4] = fmaxf(fmaf(a2.x, di, b2v.x), 0.f);
    vals[5] = fmaxf(fmaf(a2.y, di, b2v.y), 0.f);
    vals[6] = fmaxf(fmaf(a3.x, di, b3v.x), 0.f);
    vals[7] = fmaxf(fmaf(a3.y, di, b3v.y), 0.f);
    float ss = 0.f;
    #pragma unroll
    for (int j = 0; j < 8; j++) ss = fmaf(vals[j], vals[j], ss);
    #pragma unroll
    for (int m = 1; m <= 8; m <<= 1) ss += __shfl_xor(ss, m, 64);
    float scale = 1.0f / fmaxf(sqrtf(ss), 1e-12f);
    if (g == 0) {
        uint4 o;
        o.x = (uint_t)f32_to_bf16_rn(vals[0] * scale) | ((uint_t)f32_to_bf16_rn(vals[1] * scale) << 16);
        o.y = (uint_t)f32_to_bf16_rn(vals[2] * scale) | ((uint_t)f32_to_bf16_rn(vals[3] * scale) << 16);
        o.z = (uint_t)f32_to_bf16_rn(vals[4] * scale) | ((uint_t)f32_to_bf16_rn(vals[5] * scale) << 16);
        o.w = (uint_t)f32_to_bf16_rn(vals[6] * scale) | ((uint_t)f32_to_bf16_rn(vals[7] * scale) << 16);
        ((uint4*)h)[(size_t)i * 16 + cb] = o;
    }
}

// ---------------- aggregation layer 2: pull + bias -> d_out (f32) ----------------
// hw rows pre-scaled by dinv[src]; result = dinv[i]*(self + sum) + b2.
// R14: 1 node/wave, 16B/lane (8 chunk-lanes cover the 128B row), 8 edge
// groups x 4 independent gather chains (32 edges/iter); masked clamped tail.
__global__ __launch_bounds__(256) void agg2_kernel(const ushort_t* __restrict__ hw,
                                                   const int* __restrict__ csr_src,
                                                   const int* __restrict__ row_start,
                                                   const float* __restrict__ dinv,
                                                   const float* __restrict__ b2,
                                                   float* __restrict__ out, int n) {
    int wid = (blockIdx.x * 256 + threadIdx.x) >> 6;
    int lane = threadIdx.x & 63;
    if (wid >= n) return;
    int i = wid;
    int g = lane >> 3;                       // 8 edge groups
    int cb = lane & 7;                       // 8 x 16B chunks = 128B row
    const uint4* H4 = (const uint4*)hw;      // row i = H4[i*8 + cb]
    float di = dinv[i];
    int e0 = row_start[i], e1 = row_start[i + 1];

    f32v2 a0 = {0.f, 0.f}, a1 = {0.f, 0.f}, a2 = {0.f, 0.f}, a3 = {0.f, 0.f};
    // self row: group 0 contributes once
    {
        uint4 v = H4[(size_t)i * 8 + cb];
        acc_row_c(a0, a1, a2, a3, v, (g == 0) ? 1.0f : 0.0f);
    }
    int e = e0;
    // main loop: 32 edges/iter, 4 independent idx->gather chains
    for (; e + 32 <= e1; e += 32) {
        int s0 = csr_src[e + g];
        int s1 = csr_src[e + 8 + g];
        int s2 = csr_src[e + 16 + g];
        int s3 = csr_src[e + 24 + g];
        uint4 v0 = H4[(size_t)s0 * 8 + cb];
        uint4 v1 = H4[(size_t)s1 * 8 + cb];
        uint4 v2 = H4[(size_t)s2 * 8 + cb];
        uint4 v3 = H4[(size_t)s3 * 8 + cb];
        acc_row(a0, a1, a2, a3, v0);
        acc_row(a0, a1, a2, a3, v1);
        acc_row(a0, a1, a2, a3, v2);
        acc_row(a0, a1, a2, a3, v3);
    }
    // masked tail: positions clamped to last (dups L1-hot, coef 0)
    if (e < e1) {
        int last = e1 - 1;
        int p0 = e + g, p1 = e + 8 + g, p2 = e + 16 + g, p3 = e + 24 + g;
        int s0 = csr_src[p0 <= last ? p0 : last];
        int s1 = csr_src[p1 <= last ? p1 : last];
        int s2 = csr_src[p2 <= last ? p2 : last];
        int s3 = csr_src[p3 <= last ? p3 : last];
        uint4 v0 = H4[(size_t)s0 * 8 + cb];
        uint4 v1 = H4[(size_t)s1 * 8 + cb];
        uint4 v2 = H4[(size_t)s2 * 8 + cb];
        uint4 v3 = H4[(size_t)s3 * 8 + cb];
        acc_row_c(a0, a1, a2, a3, v0, (p0 <= last) ? 1.0f : 0.0f);
        acc_row_c(a0, a1, a2, a3, v1, (p1 <= last) ? 1.0f : 0.0f);
        acc_row_c(a0, a1, a2, a3, v2, (p2 <= last) ? 1.0f : 0.0f);
        acc_row_c(a0, a1, a2, a3, v3, (p3 <= last) ? 1.0f : 0.0f);
    }
    // combine the 8 edge-groups
    #pragma unroll
    for (int m = 8; m <= 32; m <<= 1) {
        a0.x += __shfl_xor(a0.x, m, 64); a0.y += __shfl_xor(a0.y, m, 64);
        a1.x += __shfl_xor(a1.x, m, 64); a1.y += __shfl_xor(a1.y, m, 64);
        a2.x += __shfl_xor(a2.x, m, 64); a2.y += __shfl_xor(a2.y, m, 64);
        a3.x += __shfl_xor(a3.x, m, 64); a3.y += __shfl_xor(a3.y, m, 64);
    }
    if (g == 0) {
        const float2* bp = (const float2*)(b2 + cb * 8);
        float2 b0v = bp[0], b1v = bp[1], b2v = bp[2], b3v = bp[3];
        float4 o0, o1;
        o0.x = fmaf(a0.x, di, b0v.x);
        o0.y = fmaf(a0.y, di, b0v.y);
        o0.z = fmaf(a1.x, di, b1v.x);
        o0.w = fmaf(a1.y, di, b1v.y);
        o1.x = fmaf(a2.x, di, b2v.x);
        o1.y = fmaf(a2.y, di, b2v.y);
        o1.z = fmaf(a3.x, di, b3v.x);
        o1.w = fmaf(a3.y, di, b3v.y);
        ((float4*)out)[(size_t)i * 16 + cb * 2]     = o0;
        ((float4*)out)[(size_t)i * 16 + cb * 2 + 1] = o1;
    }
}

extern "C" void kernel_launch(void* const* d_in, const int* in_sizes, int n_in,
                              void* d_out, int out_size, void* d_ws, size_t ws_size,
                              hipStream_t stream) {
    const float* x  = (const float*)d_in[0];
    const int*   ei = (const int*)d_in[1];
    const float* W1 = (const float*)d_in[2];
    const float* b1 = (const float*)d_in[3];
    const float* W2 = (const float*)d_in[4];
    const float* b2 = (const float*)d_in[5];
    float* out = (float*)d_out;

    const int N = in_sizes[0] / IN_CH;     // 100000
    const int E = in_sizes[1] / 2;         // 1600000
    const int* src = ei;
    const int* dst = ei + E;
    const int NB = (N + 63) / 64;          // buckets (1563)
    const int chunk = (E + NBLK - 1) / NBLK;

    // ---- workspace carve ----
    char* base = (char*)d_ws;
    size_t off = 0;
    auto alloc = [&](size_t bytes) -> void* {
        void* p = base + off;
        off = (off + bytes + 255) & ~(size_t)255;
        return p;
    };
    int*      blk_cnt     = (int*)alloc((size_t)NBLK * NB * 4);
    int*      blk_start   = (int*)alloc((size_t)NBLK * NB * 4);
    int*      btot        = (int*)alloc((size_t)NB * 4);
    int*      bucket_base = (int*)alloc((size_t)(NB + 1) * 4);
    int*      row_start   = (int*)alloc((size_t)(N + 1) * 4);
    float*    dinv        = (float*)alloc((size_t)N * 4);
    int*      csr_src     = (int*)alloc((size_t)E * 4);
    uint_t*   pairs       = (uint_t*)alloc((size_t)E * 4);
    ushort_t* xw          = (ushort_t*)alloc((size_t)N * HID * 2);
    ushort_t* h           = (ushort_t*)alloc((size_t)N * HID * 2);
    ushort_t* hw          = (ushort_t*)alloc((size_t)N * OUT_CH * 2);
    ushort_t* w1h         = (ushort_t*)alloc((size_t)128 * 128 * 2);
    ushort_t* w1l         = (ushort_t*)alloc((size_t)128 * 128 * 2);
    ushort_t* w2h         = (ushort_t*)alloc((size_t)64 * 128 * 2);
    ushort_t* w2l         = (ushort_t*)alloc((size_t)64 * 128 * 2);
    (void)ws_size;

    // W splits (tiny)
    wsplit_kernel<<<(128 * 128 + 64 * 128 + 255) / 256, 256, 0, stream>>>(
        W1, W2, w1h, w1l, w2h, w2l);

    // CSR build -- no global atomics anywhere
    hist_kernel<<<NBLK, 256, 0, stream>>>(dst, E, chunk, NB, blk_cnt);
    btot_kernel<<<(NB + 255) / 256, 256, 0, stream>>>(blk_cnt, NB, btot);
    scan_kernel<<<1, 256, 0, stream>>>(btot, NB, bucket_base, row_start, N, E);
    colscan_kernel<<<(NB + 15) / 16, 256, 0, stream>>>(blk_cnt, bucket_base, NB, blk_start);
    scatter_kernel<<<NBLK, 256, 0, stream>>>(src, dst, E, chunk, NB, blk_start, pairs);
    fine_fill_kernel<<<NB, 256, 0, stream>>>(pairs, bucket_base, row_start, dinv,
                                             csr_src, N);

    // layer 1 (MFMA, 3-term hi/lo split; xw pre-scaled by dinv[row])
    mfma_gemm_kernel<128, true><<<(N + 127) / 128, 256, 0, stream>>>(
        x, w1h, w1l, dinv, xw, N);
    agg1_kernel<<<(N * 64 + 255) / 256, 256, 0, stream>>>(xw, csr_src, row_start,
                                                          dinv, b1, h, N);
    // layer 2 (MFMA, 2-term; hw pre-scaled by dinv[row])
    mfma_gemm_kernel<64, false><<<(N + 127) / 128, 256, 0, stream>>>(
        h, w2h, w2l, dinv, hw, N);
    agg2_kernel<<<(N * 64 + 255) / 256, 256, 0, stream>>>(hw, csr_src, row_start,
                                                          dinv, b2, out, N);
}

// Round 10
// 300.766 us; speedup vs baseline: 1.0635x; 1.0205x over previous
//
#include <hip/hip_runtime.h>
#include <hip/hip_bf16.h>

// GCN encoder: 2x GCNConv, symmetric norm, relu + L2 rownorm between.
// Pull aggregation over CSR-by-dst, bf16 intermediates (f32 accumulate).
// R7: CSR built with ZERO global atomics (LDS histograms + scans).
// R8: agg loops fully batched; dinv[src] folded into GEMM epilogue.
// R9: GEMMs on MFMA 16x16x32 bf16, hi/lo split (f32-equiv accuracy).
// R10: B staged in XOR-swizzled LDS; 2 row-tiles/wave. GEMMs off the radar.
// R11: agg1 16B/lane gather: NEUTRAL => not VALU-bound.
// R12: 4 gather chains: +5% => ~3.5 TB/s L2-miss-path ceiling.
// R13: channel-half split REGRESSED: misses are compulsory random-line
//      traffic (cross-XCD duplication: each XCD touches ~86K distinct rows
//      => FETCH ~ 8 x 22MB = 177MB, matches measurement). agg1 at floor.
// R14: agg2 32-edge-iter port REGRESSED (~+10us): mean degree 16 < 32 =>
//      all work in the masked tail = 2x gather issue. Reverted.
// R15 (this round): (a) agg2 restored to R10-measured form; (b) both agg
// kernels grid-strided (2048 blocks, wave-persistent, ~12 nodes/wave) --
// kills per-block launch churn (25K short-lived blocks -> occupancy 70%),
// lets independent per-node gather chains overlap across nodes.

#define IN_CH 128
#define HID 128
#define OUT_CH 64
#define NBLK 128          // chunk blocks for hist/scatter
#define MAXNB 1568        // >= ceil(100000/64)=1563 buckets
#define AGG_BLOCKS 2048   // persistent-wave grid for agg kernels

typedef unsigned int uint_t;
typedef unsigned short ushort_t;
typedef __attribute__((ext_vector_type(8))) short bf16x8;
typedef __attribute__((ext_vector_type(4))) float f32x4;
typedef __attribute__((ext_vector_type(2))) float f32v2;

__device__ __forceinline__ ushort_t f32_to_bf16_rn(float f) {
    uint_t u = __float_as_uint(f);
    u = (u + 0x7fffu + ((u >> 16) & 1u)) >> 16;
    return (ushort_t)u;
}
__device__ __forceinline__ float bf16lo_to_f32(uint_t u) { return __uint_as_float(u << 16); }
__device__ __forceinline__ float bf16hi_to_f32(uint_t u) { return __uint_as_float(u & 0xffff0000u); }

// accumulate one 16B row-chunk (8 bf16 channels) into 4 f32v2 accumulators
__device__ __forceinline__ void acc_row(f32v2& a0, f32v2& a1, f32v2& a2, f32v2& a3,
                                        uint4 v) {
    a0 += (f32v2){bf16lo_to_f32(v.x), bf16hi_to_f32(v.x)};
    a1 += (f32v2){bf16lo_to_f32(v.y), bf16hi_to_f32(v.y)};
    a2 += (f32v2){bf16lo_to_f32(v.z), bf16hi_to_f32(v.z)};
    a3 += (f32v2){bf16lo_to_f32(v.w), bf16hi_to_f32(v.w)};
}
__device__ __forceinline__ void acc_row_c(f32v2& a0, f32v2& a1, f32v2& a2, f32v2& a3,
                                          uint4 v, float c) {
    f32v2 cv = {c, c};
    a0 += (f32v2){bf16lo_to_f32(v.x), bf16hi_to_f32(v.x)} * cv;
    a1 += (f32v2){bf16lo_to_f32(v.y), bf16hi_to_f32(v.y)} * cv;
    a2 += (f32v2){bf16lo_to_f32(v.z), bf16hi_to_f32(v.z)} * cv;
    a3 += (f32v2){bf16lo_to_f32(v.w), bf16hi_to_f32(v.w)} * cv;
}

// ---------------- phase 1: per-block LDS bucket histogram ----------------
__global__ __launch_bounds__(256) void hist_kernel(const int* __restrict__ dst, int E,
                                                   int chunk, int NB,
                                                   int* __restrict__ blk_cnt) {
    __shared__ int hist[MAXNB];
    int tid = threadIdx.x;
    int blk = blockIdx.x;
    for (int b = tid; b < NB; b += 256) hist[b] = 0;
    __syncthreads();
    int start = blk * chunk;
    int end = start + chunk; if (end > E) end = E;
    int e = start + tid;
    for (; e + 768 < end; e += 1024) {
        int d0 = dst[e], d1 = dst[e + 256], d2 = dst[e + 512], d3 = dst[e + 768];
        atomicAdd(&hist[d0 >> 6], 1);
        atomicAdd(&hist[d1 >> 6], 1);
        atomicAdd(&hist[d2 >> 6], 1);
        atomicAdd(&hist[d3 >> 6], 1);
    }
    for (; e < end; e += 256) atomicAdd(&hist[dst[e] >> 6], 1);
    __syncthreads();
    for (int b = tid; b < NB; b += 256) blk_cnt[blk * NB + b] = hist[b];
}

// ---------------- phase 2a: bucket totals (column sums) ----------------
__global__ __launch_bounds__(256) void btot_kernel(const int* __restrict__ blk_cnt,
                                                   int NB, int* __restrict__ btot) {
    int b = blockIdx.x * 256 + threadIdx.x;
    if (b < NB) {
        int sum = 0;
        #pragma unroll 8
        for (int blk = 0; blk < NBLK; blk++) sum += blk_cnt[blk * NB + b];
        btot[b] = sum;
    }
}

// ---------------- phase 2b: single-block exclusive scan over buckets --------------
__global__ __launch_bounds__(256) void scan_kernel(const int* __restrict__ btot, int NB,
                                                   int* __restrict__ bucket_base,
                                                   int* __restrict__ row_start,
                                                   int n, int E) {
    __shared__ int sdata[256];
    __shared__ int carryS;
    int tid = threadIdx.x;
    if (tid == 0) carryS = 0;
    __syncthreads();
    int nchunks = (NB + 255) / 256;
    for (int c = 0; c < nchunks; c++) {
        int i = c * 256 + tid;
        int v = (i < NB) ? btot[i] : 0;
        sdata[tid] = v;
        __syncthreads();
        for (int off = 1; off < 256; off <<= 1) {
            int t = (tid >= off) ? sdata[tid - off] : 0;
            __syncthreads();
            sdata[tid] += t;
            __syncthreads();
        }
        if (i < NB) bucket_base[i] = carryS + sdata[tid] - v;
        __syncthreads();
        if (tid == 0) carryS += sdata[255];
        __syncthreads();
    }
    if (tid == 0) {
        bucket_base[NB] = E;
        row_start[n] = E;
    }
}

// ---------------- phase 2c: per-bucket exclusive scan over blocks -----------------
__global__ __launch_bounds__(256) void colscan_kernel(const int* __restrict__ blk_cnt,
                                                      const int* __restrict__ bucket_base,
                                                      int NB, int* __restrict__ blk_start) {
    __shared__ int tile[NBLK][16];
    int tid = threadIdx.x;
    int b0 = blockIdx.x * 16;
    for (int idx = tid; idx < NBLK * 16; idx += 256) {
        int blk = idx >> 4, b = idx & 15;
        if (b0 + b < NB) tile[blk][b] = blk_cnt[blk * NB + b0 + b];
    }
    __syncthreads();
    if (tid < 16 && b0 + tid < NB) {
        int running = bucket_base[b0 + tid];
        for (int blk = 0; blk < NBLK; blk++) {
            int t = tile[blk][tid];
            tile[blk][tid] = running;
            running += t;
        }
    }
    __syncthreads();
    for (int idx = tid; idx < NBLK * 16; idx += 256) {
        int blk = idx >> 4, b = idx & 15;
        if (b0 + b < NB) blk_start[blk * NB + b0 + b] = tile[blk][b];
    }
}

// ---------------- phase 3: scatter, LDS tickets only ----------------
// pack: src (26 bits) | (dst & 63) << 26.
__global__ __launch_bounds__(256) void scatter_kernel(const int* __restrict__ src,
                                                      const int* __restrict__ dst,
                                                      int E, int chunk, int NB,
                                                      const int* __restrict__ blk_start,
                                                      uint_t* __restrict__ pairs) {
    __shared__ int cur[MAXNB];
    int tid = threadIdx.x;
    int blk = blockIdx.x;
    for (int b = tid; b < NB; b += 256) cur[b] = blk_start[blk * NB + b];
    __syncthreads();
    int start = blk * chunk;
    int end = start + chunk; if (end > E) end = E;
    int e = start + tid;
    for (; e + 768 < end; e += 1024) {
        int d0 = dst[e], d1 = dst[e + 256], d2 = dst[e + 512], d3 = dst[e + 768];
        int s0 = src[e], s1 = src[e + 256], s2 = src[e + 512], s3 = src[e + 768];
        int p0 = atomicAdd(&cur[d0 >> 6], 1);
        int p1 = atomicAdd(&cur[d1 >> 6], 1);
        int p2 = atomicAdd(&cur[d2 >> 6], 1);
        int p3 = atomicAdd(&cur[d3 >> 6], 1);
        pairs[p0] = (uint_t)s0 | ((uint_t)(d0 & 63) << 26);
        pairs[p1] = (uint_t)s1 | ((uint_t)(d1 & 63) << 26);
        pairs[p2] = (uint_t)s2 | ((uint_t)(d2 & 63) << 26);
        pairs[p3] = (uint_t)s3 | ((uint_t)(d3 & 63) << 26);
    }
    for (; e < end; e += 256) {
        int d = dst[e], s = src[e];
        int p = atomicAdd(&cur[d >> 6], 1);
        pairs[p] = (uint_t)s | ((uint_t)(d & 63) << 26);
    }
}

// ---------------- phase 4: fine fill -- per bucket: counts, row_start, dinv, csr ---
__global__ __launch_bounds__(256) void fine_fill_kernel(const uint_t* __restrict__ pairs,
                                                        const int* __restrict__ bucket_base,
                                                        int* __restrict__ row_start,
                                                        float* __restrict__ dinv,
                                                        int* __restrict__ csr_src,
                                                        int n) {
    __shared__ int cnt64[64];
    __shared__ int cur[64];
    int b = blockIdx.x;
    int node0 = b << 6;
    int tid = threadIdx.x;
    if (tid < 64) cnt64[tid] = 0;
    __syncthreads();
    int start = bucket_base[b];
    int end = bucket_base[b + 1];
    int e = start + tid;
    for (; e + 768 < end; e += 1024) {
        uint_t u0 = pairs[e], u1 = pairs[e + 256], u2 = pairs[e + 512], u3 = pairs[e + 768];
        atomicAdd(&cnt64[u0 >> 26], 1);
        atomicAdd(&cnt64[u1 >> 26], 1);
        atomicAdd(&cnt64[u2 >> 26], 1);
        atomicAdd(&cnt64[u3 >> 26], 1);
    }
    for (; e < end; e += 256) atomicAdd(&cnt64[pairs[e] >> 26], 1);
    __syncthreads();
    if (tid < 64) {
        int c = cnt64[tid];
        int v = c;
        #pragma unroll
        for (int off = 1; off < 64; off <<= 1) {
            int u = __shfl_up(v, off, 64);
            if (tid >= off) v += u;
        }
        int excl = start + v - c;
        if (node0 + tid < n) {
            row_start[node0 + tid] = excl;
            dinv[node0 + tid] = rsqrtf((float)(c + 1));  // +1 self loop
        }
        cur[tid] = excl;
    }
    __syncthreads();
    e = start + tid;
    for (; e + 768 < end; e += 1024) {
        uint_t u0 = pairs[e], u1 = pairs[e + 256], u2 = pairs[e + 512], u3 = pairs[e + 768];
        int p0 = atomicAdd(&cur[u0 >> 26], 1);
        int p1 = atomicAdd(&cur[u1 >> 26], 1);
        int p2 = atomicAdd(&cur[u2 >> 26], 1);
        int p3 = atomicAdd(&cur[u3 >> 26], 1);
        csr_src[p0] = (int)(u0 & 0x3FFFFFFu);
        csr_src[p1] = (int)(u1 & 0x3FFFFFFu);
        csr_src[p2] = (int)(u2 & 0x3FFFFFFu);
        csr_src[p3] = (int)(u3 & 0x3FFFFFFu);
    }
    for (; e < end; e += 256) {
        uint_t u = pairs[e];
        int p = atomicAdd(&cur[u >> 26], 1);
        csr_src[p] = (int)(u & 0x3FFFFFFu);
    }
}

// ---------------- W prep: transposed bf16 hi/lo splits ----------------
// w1h/w1l: [128 cols][128 k]; w2h/w2l: [64 cols][128 k]. Wt[c][k] = W[k][c].
__global__ __launch_bounds__(256) void wsplit_kernel(const float* __restrict__ W1,
                                                     const float* __restrict__ W2,
                                                     ushort_t* __restrict__ w1h,
                                                     ushort_t* __restrict__ w1l,
                                                     ushort_t* __restrict__ w2h,
                                                     ushort_t* __restrict__ w2l) {
    int idx = blockIdx.x * 256 + threadIdx.x;
    const int tot1 = 128 * 128;
    const int tot = tot1 + 64 * 128;
    if (idx >= tot) return;
    float v;
    ushort_t* ph;
    ushort_t* pl;
    int o;
    if (idx < tot1) {
        int c = idx >> 7, k = idx & 127;
        v = W1[k * 128 + c];
        ph = w1h; pl = w1l; o = idx;
    } else {
        int j = idx - tot1;
        int c = j >> 7, k = j & 127;
        v = W2[k * 64 + c];
        ph = w2h; pl = w2l; o = j;
    }
    ushort_t h = f32_to_bf16_rn(v);
    float hv = __uint_as_float((uint_t)h << 16);
    ph[o] = h;
    pl[o] = f32_to_bf16_rn(v - hv);
}

// ---------------- MFMA GEMM: Y[n x NCOL] = (X[n x 128] @ W) * rowscale[row] -------
// hi/lo split: F32_IN: 3 terms (xh*wh + xh*wl + xl*wh); bf16 in: 2 terms (exact A).
// B staged in XOR-swizzled LDS (byte ^= (row&7)<<4): conflict-free ds_read_b128,
// no L1 thrash. 4 waves x 32 rows = 128 rows/block; 2 row-tiles/wave for ILP.
// Fragment maps (v_mfma_f32_16x16x32_bf16): A row=lane&15, k=(lane>>4)*8+j;
// B col=lane&15, k=(lane>>4)*8+j; D col=lane&15, row=(lane>>4)*4+reg.
template <int NCOL, bool F32_IN>
__global__ __launch_bounds__(256, 2) void mfma_gemm_kernel(const void* __restrict__ Xv,
                                                           const ushort_t* __restrict__ Wth,
                                                           const ushort_t* __restrict__ Wtl,
                                                           const float* __restrict__ rowscale,
                                                           ushort_t* __restrict__ Y, int n) {
    constexpr int NT = NCOL / 16;          // col tiles (8 or 4)
    constexpr int WB = NCOL * 128 * 2;     // bytes per W array (h or l)
    constexpr int NCH = WB / 16;           // 16B chunks per array
    __shared__ __align__(16) char Bs[2 * WB];   // h @0, l @WB; swizzled

    int tid = threadIdx.x;

    // ---- stage B, swizzled (reg-staged: global_load_lds can't swizzle) ----
    for (int i = tid; i < 2 * NCH; i += 256) {
        bool lo = (i >= NCH);
        int j = lo ? i - NCH : i;
        int row = j >> 4, c = j & 15;        // row = W col index; 16 chunks/row
        bf16x8 v = *(const bf16x8*)((lo ? Wtl : Wth) + row * 128 + c * 8);
        int bo = (row << 8) + (c << 4);
        bo ^= (row & 7) << 4;                // T2 swizzle
        *(bf16x8*)(Bs + (lo ? WB : 0) + bo) = v;
    }
    __syncthreads();

    int wave = tid >> 6;
    int lane = tid & 63;
    int q = lane >> 4;                       // k-quarter selector
    int r16 = lane & 15;                     // A row / B,D col within tile
    int rowBase = blockIdx.x * 128 + wave * 32;
    int ar0 = rowBase + r16;      if (ar0 > n - 1) ar0 = n - 1;
    int ar1 = rowBase + 16 + r16; if (ar1 > n - 1) ar1 = n - 1;

    const float* X = (const float*)Xv;
    const ushort_t* Hb = (const ushort_t*)Xv;

    f32x4 acc[2][NT];
    #pragma unroll
    for (int rt = 0; rt < 2; rt++)
        #pragma unroll
        for (int t = 0; t < NT; t++) acc[rt][t] = (f32x4){0.f, 0.f, 0.f, 0.f};

    #pragma unroll
    for (int ks = 0; ks < 4; ks++) {
        int k0 = ks * 32 + q * 8;            // element index in K
        bf16x8 ah[2], al[2] = {};
        #pragma unroll
        for (int rt = 0; rt < 2; rt++) {
            int arow = rt ? ar1 : ar0;
            if (F32_IN) {
                const float4* xr = (const float4*)(X + (size_t)arow * 128 + k0);
                float4 p0 = xr[0], p1 = xr[1];
                float v[8] = {p0.x, p0.y, p0.z, p0.w, p1.x, p1.y, p1.z, p1.w};
                #pragma unroll
                for (int j = 0; j < 8; j++) {
                    ushort_t hb = f32_to_bf16_rn(v[j]);
                    float hv = __uint_as_float((uint_t)hb << 16);
                    ah[rt][j] = (short)hb;
                    al[rt][j] = (short)f32_to_bf16_rn(v[j] - hv);
                }
            } else {
                ah[rt] = *(const bf16x8*)(Hb + (size_t)arow * 128 + k0);
            }
        }
        #pragma unroll
        for (int t = 0; t < NT; t++) {
            int bo = ((t * 16 + r16) << 8) + ks * 64 + (q << 4);
            bo ^= (r16 & 7) << 4;            // (t*16+r16)&7 == r16&7
            bf16x8 bh = *(const bf16x8*)(Bs + bo);
            bf16x8 bl = *(const bf16x8*)(Bs + WB + bo);
            #pragma unroll
            for (int rt = 0; rt < 2; rt++) {
                acc[rt][t] = __builtin_amdgcn_mfma_f32_16x16x32_bf16(ah[rt], bh, acc[rt][t], 0, 0, 0);
                acc[rt][t] = __builtin_amdgcn_mfma_f32_16x16x32_bf16(ah[rt], bl, acc[rt][t], 0, 0, 0);
                if (F32_IN)
                    acc[rt][t] = __builtin_amdgcn_mfma_f32_16x16x32_bf16(al[rt], bh, acc[rt][t], 0, 0, 0);
            }
        }
    }

    #pragma unroll
    for (int rt = 0; rt < 2; rt++) {
        #pragma unroll
        for (int rr = 0; rr < 4; rr++) {
            int row = rowBase + rt * 16 + q * 4 + rr;
            if (row < n) {
                float rs = rowscale[row];
                #pragma unroll
                for (int t = 0; t < NT; t++)
                    Y[(size_t)row * NCOL + t * 16 + r16] = f32_to_bf16_rn(acc[rt][t][rr] * rs);
            }
        }
    }
}

// ---------------- aggregation layer 1: pull + bias + relu + L2 rownorm ----------------
// xw rows pre-scaled by dinv[src]; result = dinv[i]*(self + sum) + b1.
// R12 body (16B/lane, 16 row-chunk lanes, 4 edge-groups x 4 gather chains),
// R15: grid-strided persistent waves (~12 nodes/wave at 2048 blocks).
__global__ __launch_bounds__(256) void agg1_kernel(const ushort_t* __restrict__ xw,
                                                   const int* __restrict__ csr_src,
                                                   const int* __restrict__ row_start,
                                                   const float* __restrict__ dinv,
                                                   const float* __restrict__ b1,
                                                   ushort_t* __restrict__ h, int n) {
    int w0 = (blockIdx.x * 256 + threadIdx.x) >> 6;
    int nw = gridDim.x * 4;                  // total waves
    int lane = threadIdx.x & 63;
    int g = lane >> 4;
    int cb = lane & 15;
    const uint4* X4 = (const uint4*)xw;      // row i = X4[i*16 + cb]
    const float2* bp = (const float2*)(b1 + cb * 8);
    float2 b0v = bp[0], b1v = bp[1], b2v = bp[2], b3v = bp[3];

    for (int i = w0; i < n; i += nw) {
        float di = dinv[i];
        int e0 = row_start[i], e1 = row_start[i + 1];

        f32v2 a0 = {0.f, 0.f}, a1 = {0.f, 0.f}, a2 = {0.f, 0.f}, a3 = {0.f, 0.f};
        // self row: group 0 contributes once
        {
            uint4 v = X4[(size_t)i * 16 + cb];
            acc_row_c(a0, a1, a2, a3, v, (g == 0) ? 1.0f : 0.0f);
        }
        int e = e0;
        // main loop: 16 edges/iter, 4 independent idx->gather chains in flight
        for (; e + 16 <= e1; e += 16) {
            int s0 = csr_src[e + g];
            int s1 = csr_src[e + 4 + g];
            int s2 = csr_src[e + 8 + g];
            int s3 = csr_src[e + 12 + g];
            uint4 v0 = X4[(size_t)s0 * 16 + cb];
            uint4 v1 = X4[(size_t)s1 * 16 + cb];
            uint4 v2 = X4[(size_t)s2 * 16 + cb];
            uint4 v3 = X4[(size_t)s3 * 16 + cb];
            acc_row(a0, a1, a2, a3, v0);
            acc_row(a0, a1, a2, a3, v1);
            acc_row(a0, a1, a2, a3, v2);
            acc_row(a0, a1, a2, a3, v3);
        }
        // masked tail: same 4-chain layout, positions clamped to last
        if (e < e1) {
            int last = e1 - 1;
            int p0 = e + g, p1 = e + 4 + g, p2 = e + 8 + g, p3 = e + 12 + g;
            int s0 = csr_src[p0 <= last ? p0 : last];
            int s1 = csr_src[p1 <= last ? p1 : last];
            int s2 = csr_src[p2 <= last ? p2 : last];
            int s3 = csr_src[p3 <= last ? p3 : last];
            uint4 v0 = X4[(size_t)s0 * 16 + cb];
            uint4 v1 = X4[(size_t)s1 * 16 + cb];
            uint4 v2 = X4[(size_t)s2 * 16 + cb];
            uint4 v3 = X4[(size_t)s3 * 16 + cb];
            acc_row_c(a0, a1, a2, a3, v0, (p0 <= last) ? 1.0f : 0.0f);
            acc_row_c(a0, a1, a2, a3, v1, (p1 <= last) ? 1.0f : 0.0f);
            acc_row_c(a0, a1, a2, a3, v2, (p2 <= last) ? 1.0f : 0.0f);
            acc_row_c(a0, a1, a2, a3, v3, (p3 <= last) ? 1.0f : 0.0f);
        }
        // combine the 4 edge-groups
        #pragma unroll
        for (int m = 16; m <= 32; m <<= 1) {
            a0.x += __shfl_xor(a0.x, m, 64); a0.y += __shfl_xor(a0.y, m, 64);
            a1.x += __shfl_xor(a1.x, m, 64); a1.y += __shfl_xor(a1.y, m, 64);
            a2.x += __shfl_xor(a2.x, m, 64); a2.y += __shfl_xor(a2.y, m, 64);
            a3.x += __shfl_xor(a3.x, m, 64); a3.y += __shfl_xor(a3.y, m, 64);
        }
        // bias + relu for channels cb*8 .. cb*8+7
        float vals[8];
        vals[0] = fmaxf(fmaf(a0.x, di, b0v.x), 0.f);
        vals[1] = fmaxf(fmaf(a0.y, di, b0v.y), 0.f);
        vals[2] = fmaxf(fmaf(a1.x, di, b1v.x), 0.f);
        vals[3] = fmaxf(fmaf(a1.y, di, b1v.y), 0.f);
        vals[4] = fmaxf(fmaf(a2.x, di, b2v.x), 0.f);
        vals[5] = fmaxf(fmaf(a2.y, di, b2v.y), 0.f);
        vals[6] = fmaxf(fmaf(a3.x, di, b3v.x), 0.f);
        vals[7] = fmaxf(fmaf(a3.y, di, b3v.y), 0.f);
        float ss = 0.f;
        #pragma unroll
        for (int j = 0; j < 8; j++) ss = fmaf(vals[j], vals[j], ss);
        #pragma unroll
        for (int m = 1; m <= 8; m <<= 1) ss += __shfl_xor(ss, m, 64);
        float scale = 1.0f / fmaxf(sqrtf(ss), 1e-12f);
        if (g == 0) {
            uint4 o;
            o.x = (uint_t)f32_to_bf16_rn(vals[0] * scale) | ((uint_t)f32_to_bf16_rn(vals[1] * scale) << 16);
            o.y = (uint_t)f32_to_bf16_rn(vals[2] * scale) | ((uint_t)f32_to_bf16_rn(vals[3] * scale) << 16);
            o.z = (uint_t)f32_to_bf16_rn(vals[4] * scale) | ((uint_t)f32_to_bf16_rn(vals[5] * scale) << 16);
            o.w = (uint_t)f32_to_bf16_rn(vals[6] * scale) | ((uint_t)f32_to_bf16_rn(vals[7] * scale) << 16);
            ((uint4*)h)[(size_t)i * 16 + cb] = o;
        }
    }
}

// ---------------- aggregation layer 2: pull + bias -> d_out (f32) ----------------
// hw rows pre-scaled by dinv[src]; result = dinv[i]*(self + sum) + b2.
// R10-measured body (2 nodes/wave, 32 lanes each, 8-edge batches);
// R15: grid-strided persistent waves.
__global__ __launch_bounds__(256) void agg2_kernel(const ushort_t* __restrict__ hw,
                                                   const int* __restrict__ csr_src,
                                                   const int* __restrict__ row_start,
                                                   const float* __restrict__ dinv,
                                                   const float* __restrict__ b2,
                                                   float* __restrict__ out, int n) {
    int w0 = (blockIdx.x * 256 + threadIdx.x) >> 6;
    int nw = gridDim.x * 4;                  // total waves
    int lane = threadIdx.x & 63;
    int half = lane >> 5;
    int l = lane & 31;
    float bx = b2[l * 2], by = b2[l * 2 + 1];

    for (int w = w0; w * 2 < n; w += nw) {
        int i = w * 2 + half;
        if (i >= n) continue;
        float di = dinv[i];
        uint_t su = ((const uint_t*)(hw + (size_t)i * OUT_CH))[l];
        float ax = bf16lo_to_f32(su), ay = bf16hi_to_f32(su);
        int e0 = row_start[i], e1 = row_start[i + 1];
        int e = e0;
        for (; e + 8 <= e1; e += 8) {
            int s[8];
            #pragma unroll
            for (int j = 0; j < 8; j++) s[j] = csr_src[e + j];
            uint_t v[8];
            #pragma unroll
            for (int j = 0; j < 8; j++)
                v[j] = ((const uint_t*)(hw + (size_t)s[j] * OUT_CH))[l];
            #pragma unroll
            for (int j = 0; j < 8; j++) {
                ax += bf16lo_to_f32(v[j]);
                ay += bf16hi_to_f32(v[j]);
            }
        }
        if (e < e1) {
            int last = e1 - 1;
            int s[8];
            #pragma unroll
            for (int j = 0; j < 8; j++) {
                int idx = e + j;
                s[j] = csr_src[idx <= last ? idx : last];
            }
            uint_t v[8];
            #pragma unroll
            for (int j = 0; j < 8; j++)
                v[j] = ((const uint_t*)(hw + (size_t)s[j] * OUT_CH))[l];
            #pragma unroll
            for (int j = 0; j < 8; j++) {
                float c = (e + j <= last) ? 1.0f : 0.0f;
                ax = fmaf(bf16lo_to_f32(v[j]), c, ax);
                ay = fmaf(bf16hi_to_f32(v[j]), c, ay);
            }
        }
        ax = fmaf(ax, di, bx);
        ay = fmaf(ay, di, by);
        ((float2*)(out + (size_t)i * OUT_CH))[l] = make_float2(ax, ay);
    }
}

extern "C" void kernel_launch(void* const* d_in, const int* in_sizes, int n_in,
                              void* d_out, int out_size, void* d_ws, size_t ws_size,
                              hipStream_t stream) {
    const float* x  = (const float*)d_in[0];
    const int*   ei = (const int*)d_in[1];
    const float* W1 = (const float*)d_in[2];
    const float* b1 = (const float*)d_in[3];
    const float* W2 = (const float*)d_in[4];
    const float* b2 = (const float*)d_in[5];
    float* out = (float*)d_out;

    const int N = in_sizes[0] / IN_CH;     // 100000
    const int E = in_sizes[1] / 2;         // 1600000
    const int* src = ei;
    const int* dst = ei + E;
    const int NB = (N + 63) / 64;          // buckets (1563)
    const int chunk = (E + NBLK - 1) / NBLK;

    // ---- workspace carve ----
    char* base = (char*)d_ws;
    size_t off = 0;
    auto alloc = [&](size_t bytes) -> void* {
        void* p = base + off;
        off = (off + bytes + 255) & ~(size_t)255;
        return p;
    };
    int*      blk_cnt     = (int*)alloc((size_t)NBLK * NB * 4);
    int*      blk_start   = (int*)alloc((size_t)NBLK * NB * 4);
    int*      btot        = (int*)alloc((size_t)NB * 4);
    int*      bucket_base = (int*)alloc((size_t)(NB + 1) * 4);
    int*      row_start   = (int*)alloc((size_t)(N + 1) * 4);
    float*    dinv        = (float*)alloc((size_t)N * 4);
    int*      csr_src     = (int*)alloc((size_t)E * 4);
    uint_t*   pairs       = (uint_t*)alloc((size_t)E * 4);
    ushort_t* xw          = (ushort_t*)alloc((size_t)N * HID * 2);
    ushort_t* h           = (ushort_t*)alloc((size_t)N * HID * 2);
    ushort_t* hw          = (ushort_t*)alloc((size_t)N * OUT_CH * 2);
    ushort_t* w1h         = (ushort_t*)alloc((size_t)128 * 128 * 2);
    ushort_t* w1l         = (ushort_t*)alloc((size_t)128 * 128 * 2);
    ushort_t* w2h         = (ushort_t*)alloc((size_t)64 * 128 * 2);
    ushort_t* w2l         = (ushort_t*)alloc((size_t)64 * 128 * 2);
    (void)ws_size;

    // W splits (tiny)
    wsplit_kernel<<<(128 * 128 + 64 * 128 + 255) / 256, 256, 0, stream>>>(
        W1, W2, w1h, w1l, w2h, w2l);

    // CSR build -- no global atomics anywhere
    hist_kernel<<<NBLK, 256, 0, stream>>>(dst, E, chunk, NB, blk_cnt);
    btot_kernel<<<(NB + 255) / 256, 256, 0, stream>>>(blk_cnt, NB, btot);
    scan_kernel<<<1, 256, 0, stream>>>(btot, NB, bucket_base, row_start, N, E);
    colscan_kernel<<<(NB + 15) / 16, 256, 0, stream>>>(blk_cnt, bucket_base, NB, blk_start);
    scatter_kernel<<<NBLK, 256, 0, stream>>>(src, dst, E, chunk, NB, blk_start, pairs);
    fine_fill_kernel<<<NB, 256, 0, stream>>>(pairs, bucket_base, row_start, dinv,
                                             csr_src, N);

    // layer 1 (MFMA, 3-term hi/lo split; xw pre-scaled by dinv[row])
    mfma_gemm_kernel<128, true><<<(N + 127) / 128, 256, 0, stream>>>(
        x, w1h, w1l, dinv, xw, N);
    agg1_kernel<<<AGG_BLOCKS, 256, 0, stream>>>(xw, csr_src, row_start,
                                                dinv, b1, h, N);
    // layer 2 (MFMA, 2-term; hw pre-scaled by dinv[row])
    mfma_gemm_kernel<64, false><<<(N + 127) / 128, 256, 0, stream>>>(
        h, w2h, w2l, dinv, hw, N);
    agg2_kernel<<<AGG_BLOCKS, 256, 0, stream>>>(hw, csr_src, row_start,
                                                dinv, b2, out, N);
}

// Round 11
// 289.885 us; speedup vs baseline: 1.1035x; 1.0375x over previous
//
#include <hip/hip_runtime.h>
#include <hip/hip_bf16.h>

// GCN encoder: 2x GCNConv, symmetric norm, relu + L2 rownorm between.
// Pull aggregation over CSR-by-dst, bf16 intermediates (f32 accumulate).
// R7: CSR built with ZERO global atomics (LDS histograms + scans).
// R8: agg loops fully batched; dinv[src] folded into GEMM epilogue.
// R9: GEMMs on MFMA 16x16x32 bf16, hi/lo split (f32-equiv accuracy).
// R10: B staged in XOR-swizzled LDS; 2 row-tiles/wave. GEMMs off the radar.
// R11: agg1 16B/lane gather: NEUTRAL => not VALU-bound.
// R12: 4 gather chains: +5% => ~3.5 TB/s L2-miss-path ceiling.
// R13: channel-half split REGRESSED: misses are compulsory random-line
//      traffic (cross-XCD duplication: FETCH ~ 8 x 24MB = 190MB, structural
//      for a random graph). agg1 at floor.
// R14: agg2 32-edge-iter port REGRESSED (tail-dominated at mean degree 16).
// R15: grid-stride persistent waves REGRESSED agg1 62->76us (VGPR 24->40,
//      occupancy 69->43%): block churn WAS the load balancer. Reverted.
// R16 (this round): best-measured components restored -- agg1 = R12 body
// (62.3us), agg2 = R10 body. agg1 floor arithmetic: (190MB fetch + 25MB
// write) / ~3.5TB/s fabric ~ 61us ~ measured. No further agg levers known.

#define IN_CH 128
#define HID 128
#define OUT_CH 64
#define NBLK 128          // chunk blocks for hist/scatter
#define MAXNB 1568        // >= ceil(100000/64)=1563 buckets

typedef unsigned int uint_t;
typedef unsigned short ushort_t;
typedef __attribute__((ext_vector_type(8))) short bf16x8;
typedef __attribute__((ext_vector_type(4))) float f32x4;
typedef __attribute__((ext_vector_type(2))) float f32v2;

__device__ __forceinline__ ushort_t f32_to_bf16_rn(float f) {
    uint_t u = __float_as_uint(f);
    u = (u + 0x7fffu + ((u >> 16) & 1u)) >> 16;
    return (ushort_t)u;
}
__device__ __forceinline__ float bf16lo_to_f32(uint_t u) { return __uint_as_float(u << 16); }
__device__ __forceinline__ float bf16hi_to_f32(uint_t u) { return __uint_as_float(u & 0xffff0000u); }

// accumulate one 16B row-chunk (8 bf16 channels) into 4 f32v2 accumulators
__device__ __forceinline__ void acc_row(f32v2& a0, f32v2& a1, f32v2& a2, f32v2& a3,
                                        uint4 v) {
    a0 += (f32v2){bf16lo_to_f32(v.x), bf16hi_to_f32(v.x)};
    a1 += (f32v2){bf16lo_to_f32(v.y), bf16hi_to_f32(v.y)};
    a2 += (f32v2){bf16lo_to_f32(v.z), bf16hi_to_f32(v.z)};
    a3 += (f32v2){bf16lo_to_f32(v.w), bf16hi_to_f32(v.w)};
}
__device__ __forceinline__ void acc_row_c(f32v2& a0, f32v2& a1, f32v2& a2, f32v2& a3,
                                          uint4 v, float c) {
    f32v2 cv = {c, c};
    a0 += (f32v2){bf16lo_to_f32(v.x), bf16hi_to_f32(v.x)} * cv;
    a1 += (f32v2){bf16lo_to_f32(v.y), bf16hi_to_f32(v.y)} * cv;
    a2 += (f32v2){bf16lo_to_f32(v.z), bf16hi_to_f32(v.z)} * cv;
    a3 += (f32v2){bf16lo_to_f32(v.w), bf16hi_to_f32(v.w)} * cv;
}

// ---------------- phase 1: per-block LDS bucket histogram ----------------
__global__ __launch_bounds__(256) void hist_kernel(const int* __restrict__ dst, int E,
                                                   int chunk, int NB,
                                                   int* __restrict__ blk_cnt) {
    __shared__ int hist[MAXNB];
    int tid = threadIdx.x;
    int blk = blockIdx.x;
    for (int b = tid; b < NB; b += 256) hist[b] = 0;
    __syncthreads();
    int start = blk * chunk;
    int end = start + chunk; if (end > E) end = E;
    int e = start + tid;
    for (; e + 768 < end; e += 1024) {
        int d0 = dst[e], d1 = dst[e + 256], d2 = dst[e + 512], d3 = dst[e + 768];
        atomicAdd(&hist[d0 >> 6], 1);
        atomicAdd(&hist[d1 >> 6], 1);
        atomicAdd(&hist[d2 >> 6], 1);
        atomicAdd(&hist[d3 >> 6], 1);
    }
    for (; e < end; e += 256) atomicAdd(&hist[dst[e] >> 6], 1);
    __syncthreads();
    for (int b = tid; b < NB; b += 256) blk_cnt[blk * NB + b] = hist[b];
}

// ---------------- phase 2a: bucket totals (column sums) ----------------
__global__ __launch_bounds__(256) void btot_kernel(const int* __restrict__ blk_cnt,
                                                   int NB, int* __restrict__ btot) {
    int b = blockIdx.x * 256 + threadIdx.x;
    if (b < NB) {
        int sum = 0;
        #pragma unroll 8
        for (int blk = 0; blk < NBLK; blk++) sum += blk_cnt[blk * NB + b];
        btot[b] = sum;
    }
}

// ---------------- phase 2b: single-block exclusive scan over buckets --------------
__global__ __launch_bounds__(256) void scan_kernel(const int* __restrict__ btot, int NB,
                                                   int* __restrict__ bucket_base,
                                                   int* __restrict__ row_start,
                                                   int n, int E) {
    __shared__ int sdata[256];
    __shared__ int carryS;
    int tid = threadIdx.x;
    if (tid == 0) carryS = 0;
    __syncthreads();
    int nchunks = (NB + 255) / 256;
    for (int c = 0; c < nchunks; c++) {
        int i = c * 256 + tid;
        int v = (i < NB) ? btot[i] : 0;
        sdata[tid] = v;
        __syncthreads();
        for (int off = 1; off < 256; off <<= 1) {
            int t = (tid >= off) ? sdata[tid - off] : 0;
            __syncthreads();
            sdata[tid] += t;
            __syncthreads();
        }
        if (i < NB) bucket_base[i] = carryS + sdata[tid] - v;
        __syncthreads();
        if (tid == 0) carryS += sdata[255];
        __syncthreads();
    }
    if (tid == 0) {
        bucket_base[NB] = E;
        row_start[n] = E;
    }
}

// ---------------- phase 2c: per-bucket exclusive scan over blocks -----------------
__global__ __launch_bounds__(256) void colscan_kernel(const int* __restrict__ blk_cnt,
                                                      const int* __restrict__ bucket_base,
                                                      int NB, int* __restrict__ blk_start) {
    __shared__ int tile[NBLK][16];
    int tid = threadIdx.x;
    int b0 = blockIdx.x * 16;
    for (int idx = tid; idx < NBLK * 16; idx += 256) {
        int blk = idx >> 4, b = idx & 15;
        if (b0 + b < NB) tile[blk][b] = blk_cnt[blk * NB + b0 + b];
    }
    __syncthreads();
    if (tid < 16 && b0 + tid < NB) {
        int running = bucket_base[b0 + tid];
        for (int blk = 0; blk < NBLK; blk++) {
            int t = tile[blk][tid];
            tile[blk][tid] = running;
            running += t;
        }
    }
    __syncthreads();
    for (int idx = tid; idx < NBLK * 16; idx += 256) {
        int blk = idx >> 4, b = idx & 15;
        if (b0 + b < NB) blk_start[blk * NB + b0 + b] = tile[blk][b];
    }
}

// ---------------- phase 3: scatter, LDS tickets only ----------------
// pack: src (26 bits) | (dst & 63) << 26.
__global__ __launch_bounds__(256) void scatter_kernel(const int* __restrict__ src,
                                                      const int* __restrict__ dst,
                                                      int E, int chunk, int NB,
                                                      const int* __restrict__ blk_start,
                                                      uint_t* __restrict__ pairs) {
    __shared__ int cur[MAXNB];
    int tid = threadIdx.x;
    int blk = blockIdx.x;
    for (int b = tid; b < NB; b += 256) cur[b] = blk_start[blk * NB + b];
    __syncthreads();
    int start = blk * chunk;
    int end = start + chunk; if (end > E) end = E;
    int e = start + tid;
    for (; e + 768 < end; e += 1024) {
        int d0 = dst[e], d1 = dst[e + 256], d2 = dst[e + 512], d3 = dst[e + 768];
        int s0 = src[e], s1 = src[e + 256], s2 = src[e + 512], s3 = src[e + 768];
        int p0 = atomicAdd(&cur[d0 >> 6], 1);
        int p1 = atomicAdd(&cur[d1 >> 6], 1);
        int p2 = atomicAdd(&cur[d2 >> 6], 1);
        int p3 = atomicAdd(&cur[d3 >> 6], 1);
        pairs[p0] = (uint_t)s0 | ((uint_t)(d0 & 63) << 26);
        pairs[p1] = (uint_t)s1 | ((uint_t)(d1 & 63) << 26);
        pairs[p2] = (uint_t)s2 | ((uint_t)(d2 & 63) << 26);
        pairs[p3] = (uint_t)s3 | ((uint_t)(d3 & 63) << 26);
    }
    for (; e < end; e += 256) {
        int d = dst[e], s = src[e];
        int p = atomicAdd(&cur[d >> 6], 1);
        pairs[p] = (uint_t)s | ((uint_t)(d & 63) << 26);
    }
}

// ---------------- phase 4: fine fill -- per bucket: counts, row_start, dinv, csr ---
__global__ __launch_bounds__(256) void fine_fill_kernel(const uint_t* __restrict__ pairs,
                                                        const int* __restrict__ bucket_base,
                                                        int* __restrict__ row_start,
                                                        float* __restrict__ dinv,
                                                        int* __restrict__ csr_src,
                                                        int n) {
    __shared__ int cnt64[64];
    __shared__ int cur[64];
    int b = blockIdx.x;
    int node0 = b << 6;
    int tid = threadIdx.x;
    if (tid < 64) cnt64[tid] = 0;
    __syncthreads();
    int start = bucket_base[b];
    int end = bucket_base[b + 1];
    int e = start + tid;
    for (; e + 768 < end; e += 1024) {
        uint_t u0 = pairs[e], u1 = pairs[e + 256], u2 = pairs[e + 512], u3 = pairs[e + 768];
        atomicAdd(&cnt64[u0 >> 26], 1);
        atomicAdd(&cnt64[u1 >> 26], 1);
        atomicAdd(&cnt64[u2 >> 26], 1);
        atomicAdd(&cnt64[u3 >> 26], 1);
    }
    for (; e < end; e += 256) atomicAdd(&cnt64[pairs[e] >> 26], 1);
    __syncthreads();
    if (tid < 64) {
        int c = cnt64[tid];
        int v = c;
        #pragma unroll
        for (int off = 1; off < 64; off <<= 1) {
            int u = __shfl_up(v, off, 64);
            if (tid >= off) v += u;
        }
        int excl = start + v - c;
        if (node0 + tid < n) {
            row_start[node0 + tid] = excl;
            dinv[node0 + tid] = rsqrtf((float)(c + 1));  // +1 self loop
        }
        cur[tid] = excl;
    }
    __syncthreads();
    e = start + tid;
    for (; e + 768 < end; e += 1024) {
        uint_t u0 = pairs[e], u1 = pairs[e + 256], u2 = pairs[e + 512], u3 = pairs[e + 768];
        int p0 = atomicAdd(&cur[u0 >> 26], 1);
        int p1 = atomicAdd(&cur[u1 >> 26], 1);
        int p2 = atomicAdd(&cur[u2 >> 26], 1);
        int p3 = atomicAdd(&cur[u3 >> 26], 1);
        csr_src[p0] = (int)(u0 & 0x3FFFFFFu);
        csr_src[p1] = (int)(u1 & 0x3FFFFFFu);
        csr_src[p2] = (int)(u2 & 0x3FFFFFFu);
        csr_src[p3] = (int)(u3 & 0x3FFFFFFu);
    }
    for (; e < end; e += 256) {
        uint_t u = pairs[e];
        int p = atomicAdd(&cur[u >> 26], 1);
        csr_src[p] = (int)(u & 0x3FFFFFFu);
    }
}

// ---------------- W prep: transposed bf16 hi/lo splits ----------------
// w1h/w1l: [128 cols][128 k]; w2h/w2l: [64 cols][128 k]. Wt[c][k] = W[k][c].
__global__ __launch_bounds__(256) void wsplit_kernel(const float* __restrict__ W1,
                                                     const float* __restrict__ W2,
                                                     ushort_t* __restrict__ w1h,
                                                     ushort_t* __restrict__ w1l,
                                                     ushort_t* __restrict__ w2h,
                                                     ushort_t* __restrict__ w2l) {
    int idx = blockIdx.x * 256 + threadIdx.x;
    const int tot1 = 128 * 128;
    const int tot = tot1 + 64 * 128;
    if (idx >= tot) return;
    float v;
    ushort_t* ph;
    ushort_t* pl;
    int o;
    if (idx < tot1) {
        int c = idx >> 7, k = idx & 127;
        v = W1[k * 128 + c];
        ph = w1h; pl = w1l; o = idx;
    } else {
        int j = idx - tot1;
        int c = j >> 7, k = j & 127;
        v = W2[k * 64 + c];
        ph = w2h; pl = w2l; o = j;
    }
    ushort_t h = f32_to_bf16_rn(v);
    float hv = __uint_as_float((uint_t)h << 16);
    ph[o] = h;
    pl[o] = f32_to_bf16_rn(v - hv);
}

// ---------------- MFMA GEMM: Y[n x NCOL] = (X[n x 128] @ W) * rowscale[row] -------
// hi/lo split: F32_IN: 3 terms (xh*wh + xh*wl + xl*wh); bf16 in: 2 terms (exact A).
// B staged in XOR-swizzled LDS (byte ^= (row&7)<<4): conflict-free ds_read_b128,
// no L1 thrash. 4 waves x 32 rows = 128 rows/block; 2 row-tiles/wave for ILP.
// Fragment maps (v_mfma_f32_16x16x32_bf16): A row=lane&15, k=(lane>>4)*8+j;
// B col=lane&15, k=(lane>>4)*8+j; D col=lane&15, row=(lane>>4)*4+reg.
template <int NCOL, bool F32_IN>
__global__ __launch_bounds__(256, 2) void mfma_gemm_kernel(const void* __restrict__ Xv,
                                                           const ushort_t* __restrict__ Wth,
                                                           const ushort_t* __restrict__ Wtl,
                                                           const float* __restrict__ rowscale,
                                                           ushort_t* __restrict__ Y, int n) {
    constexpr int NT = NCOL / 16;          // col tiles (8 or 4)
    constexpr int WB = NCOL * 128 * 2;     // bytes per W array (h or l)
    constexpr int NCH = WB / 16;           // 16B chunks per array
    __shared__ __align__(16) char Bs[2 * WB];   // h @0, l @WB; swizzled

    int tid = threadIdx.x;

    // ---- stage B, swizzled (reg-staged: global_load_lds can't swizzle) ----
    for (int i = tid; i < 2 * NCH; i += 256) {
        bool lo = (i >= NCH);
        int j = lo ? i - NCH : i;
        int row = j >> 4, c = j & 15;        // row = W col index; 16 chunks/row
        bf16x8 v = *(const bf16x8*)((lo ? Wtl : Wth) + row * 128 + c * 8);
        int bo = (row << 8) + (c << 4);
        bo ^= (row & 7) << 4;                // T2 swizzle
        *(bf16x8*)(Bs + (lo ? WB : 0) + bo) = v;
    }
    __syncthreads();

    int wave = tid >> 6;
    int lane = tid & 63;
    int q = lane >> 4;                       // k-quarter selector
    int r16 = lane & 15;                     // A row / B,D col within tile
    int rowBase = blockIdx.x * 128 + wave * 32;
    int ar0 = rowBase + r16;      if (ar0 > n - 1) ar0 = n - 1;
    int ar1 = rowBase + 16 + r16; if (ar1 > n - 1) ar1 = n - 1;

    const float* X = (const float*)Xv;
    const ushort_t* Hb = (const ushort_t*)Xv;

    f32x4 acc[2][NT];
    #pragma unroll
    for (int rt = 0; rt < 2; rt++)
        #pragma unroll
        for (int t = 0; t < NT; t++) acc[rt][t] = (f32x4){0.f, 0.f, 0.f, 0.f};

    #pragma unroll
    for (int ks = 0; ks < 4; ks++) {
        int k0 = ks * 32 + q * 8;            // element index in K
        bf16x8 ah[2], al[2] = {};
        #pragma unroll
        for (int rt = 0; rt < 2; rt++) {
            int arow = rt ? ar1 : ar0;
            if (F32_IN) {
                const float4* xr = (const float4*)(X + (size_t)arow * 128 + k0);
                float4 p0 = xr[0], p1 = xr[1];
                float v[8] = {p0.x, p0.y, p0.z, p0.w, p1.x, p1.y, p1.z, p1.w};
                #pragma unroll
                for (int j = 0; j < 8; j++) {
                    ushort_t hb = f32_to_bf16_rn(v[j]);
                    float hv = __uint_as_float((uint_t)hb << 16);
                    ah[rt][j] = (short)hb;
                    al[rt][j] = (short)f32_to_bf16_rn(v[j] - hv);
                }
            } else {
                ah[rt] = *(const bf16x8*)(Hb + (size_t)arow * 128 + k0);
            }
        }
        #pragma unroll
        for (int t = 0; t < NT; t++) {
            int bo = ((t * 16 + r16) << 8) + ks * 64 + (q << 4);
            bo ^= (r16 & 7) << 4;            // (t*16+r16)&7 == r16&7
            bf16x8 bh = *(const bf16x8*)(Bs + bo);
            bf16x8 bl = *(const bf16x8*)(Bs + WB + bo);
            #pragma unroll
            for (int rt = 0; rt < 2; rt++) {
                acc[rt][t] = __builtin_amdgcn_mfma_f32_16x16x32_bf16(ah[rt], bh, acc[rt][t], 0, 0, 0);
                acc[rt][t] = __builtin_amdgcn_mfma_f32_16x16x32_bf16(ah[rt], bl, acc[rt][t], 0, 0, 0);
                if (F32_IN)
                    acc[rt][t] = __builtin_amdgcn_mfma_f32_16x16x32_bf16(al[rt], bh, acc[rt][t], 0, 0, 0);
            }
        }
    }

    #pragma unroll
    for (int rt = 0; rt < 2; rt++) {
        #pragma unroll
        for (int rr = 0; rr < 4; rr++) {
            int row = rowBase + rt * 16 + q * 4 + rr;
            if (row < n) {
                float rs = rowscale[row];
                #pragma unroll
                for (int t = 0; t < NT; t++)
                    Y[(size_t)row * NCOL + t * 16 + r16] = f32_to_bf16_rn(acc[rt][t][rr] * rs);
            }
        }
    }
}

// ---------------- aggregation layer 1: pull + bias + relu + L2 rownorm ----------------
// xw rows pre-scaled by dinv[src]; result = dinv[i]*(self + sum) + b1.
// R12 body (best measured 62.3us): 16B/lane gather, 16 row-chunk lanes,
// 4 edge-groups x 4 independent gather chains; masked clamped tail.
__global__ __launch_bounds__(256) void agg1_kernel(const ushort_t* __restrict__ xw,
                                                   const int* __restrict__ csr_src,
                                                   const int* __restrict__ row_start,
                                                   const float* __restrict__ dinv,
                                                   const float* __restrict__ b1,
                                                   ushort_t* __restrict__ h, int n) {
    int wid = (blockIdx.x * 256 + threadIdx.x) >> 6;
    int lane = threadIdx.x & 63;
    if (wid >= n) return;
    int i = wid;
    int g = lane >> 4;
    int cb = lane & 15;
    const uint4* X4 = (const uint4*)xw;      // row i = X4[i*16 + cb]
    float di = dinv[i];
    int e0 = row_start[i], e1 = row_start[i + 1];

    f32v2 a0 = {0.f, 0.f}, a1 = {0.f, 0.f}, a2 = {0.f, 0.f}, a3 = {0.f, 0.f};
    // self row: group 0 contributes once
    {
        uint4 v = X4[(size_t)i * 16 + cb];
        acc_row_c(a0, a1, a2, a3, v, (g == 0) ? 1.0f : 0.0f);
    }
    int e = e0;
    // main loop: 16 edges/iter, 4 independent idx->gather chains in flight
    for (; e + 16 <= e1; e += 16) {
        int s0 = csr_src[e + g];
        int s1 = csr_src[e + 4 + g];
        int s2 = csr_src[e + 8 + g];
        int s3 = csr_src[e + 12 + g];
        uint4 v0 = X4[(size_t)s0 * 16 + cb];
        uint4 v1 = X4[(size_t)s1 * 16 + cb];
        uint4 v2 = X4[(size_t)s2 * 16 + cb];
        uint4 v3 = X4[(size_t)s3 * 16 + cb];
        acc_row(a0, a1, a2, a3, v0);
        acc_row(a0, a1, a2, a3, v1);
        acc_row(a0, a1, a2, a3, v2);
        acc_row(a0, a1, a2, a3, v3);
    }
    // masked tail: same 4-chain layout, positions clamped to last
    if (e < e1) {
        int last = e1 - 1;
        int p0 = e + g, p1 = e + 4 + g, p2 = e + 8 + g, p3 = e + 12 + g;
        int s0 = csr_src[p0 <= last ? p0 : last];
        int s1 = csr_src[p1 <= last ? p1 : last];
        int s2 = csr_src[p2 <= last ? p2 : last];
        int s3 = csr_src[p3 <= last ? p3 : last];
        uint4 v0 = X4[(size_t)s0 * 16 + cb];
        uint4 v1 = X4[(size_t)s1 * 16 + cb];
        uint4 v2 = X4[(size_t)s2 * 16 + cb];
        uint4 v3 = X4[(size_t)s3 * 16 + cb];
        acc_row_c(a0, a1, a2, a3, v0, (p0 <= last) ? 1.0f : 0.0f);
        acc_row_c(a0, a1, a2, a3, v1, (p1 <= last) ? 1.0f : 0.0f);
        acc_row_c(a0, a1, a2, a3, v2, (p2 <= last) ? 1.0f : 0.0f);
        acc_row_c(a0, a1, a2, a3, v3, (p3 <= last) ? 1.0f : 0.0f);
    }
    // combine the 4 edge-groups
    #pragma unroll
    for (int m = 16; m <= 32; m <<= 1) {
        a0.x += __shfl_xor(a0.x, m, 64); a0.y += __shfl_xor(a0.y, m, 64);
        a1.x += __shfl_xor(a1.x, m, 64); a1.y += __shfl_xor(a1.y, m, 64);
        a2.x += __shfl_xor(a2.x, m, 64); a2.y += __shfl_xor(a2.y, m, 64);
        a3.x += __shfl_xor(a3.x, m, 64); a3.y += __shfl_xor(a3.y, m, 64);
    }
    // bias + relu for channels cb*8 .. cb*8+7
    const float2* bp = (const float2*)(b1 + cb * 8);
    float2 b0v = bp[0], b1v = bp[1], b2v = bp[2], b3v = bp[3];
    float vals[8];
    vals[0] = fmaxf(fmaf(a0.x, di, b0v.x), 0.f);
    vals[1] = fmaxf(fmaf(a0.y, di, b0v.y), 0.f);
    vals[2] = fmaxf(fmaf(a1.x, di, b1v.x), 0.f);
    vals[3] = fmaxf(fmaf(a1.y, di, b1v.y), 0.f);
    vals[4] = fmaxf(fmaf(a2.x, di, b2v.x), 0.f);
    vals[5] = fmaxf(fmaf(a2.y, di, b2v.y), 0.f);
    vals[6] = fmaxf(fmaf(a3.x, di, b3v.x), 0.f);
    vals[7] = fmaxf(fmaf(a3.y, di, b3v.y), 0.f);
    float ss = 0.f;
    #pragma unroll
    for (int j = 0; j < 8; j++) ss = fmaf(vals[j], vals[j], ss);
    #pragma unroll
    for (int m = 1; m <= 8; m <<= 1) ss += __shfl_xor(ss, m, 64);
    float scale = 1.0f / fmaxf(sqrtf(ss), 1e-12f);
    if (g == 0) {
        uint4 o;
        o.x = (uint_t)f32_to_bf16_rn(vals[0] * scale) | ((uint_t)f32_to_bf16_rn(vals[1] * scale) << 16);
        o.y = (uint_t)f32_to_bf16_rn(vals[2] * scale) | ((uint_t)f32_to_bf16_rn(vals[3] * scale) << 16);
        o.z = (uint_t)f32_to_bf16_rn(vals[4] * scale) | ((uint_t)f32_to_bf16_rn(vals[5] * scale) << 16);
        o.w = (uint_t)f32_to_bf16_rn(vals[6] * scale) | ((uint_t)f32_to_bf16_rn(vals[7] * scale) << 16);
        ((uint4*)h)[(size_t)i * 16 + cb] = o;
    }
}

// ---------------- aggregation layer 2: pull + bias -> d_out (f32) ----------------
// hw rows pre-scaled by dinv[src]; result = dinv[i]*(self + sum) + b2.
// R10-measured body: 2 nodes/wave, 32 lanes each, 8-edge batches, masked tail.
__global__ __launch_bounds__(256) void agg2_kernel(const ushort_t* __restrict__ hw,
                                                   const int* __restrict__ csr_src,
                                                   const int* __restrict__ row_start,
                                                   const float* __restrict__ dinv,
                                                   const float* __restrict__ b2,
                                                   float* __restrict__ out, int n) {
    int wid = (blockIdx.x * 256 + threadIdx.x) >> 6;
    int lane = threadIdx.x & 63;
    int i = wid * 2 + (lane >> 5);
    int l = lane & 31;
    if (i >= n) return;
    float di = dinv[i];
    uint_t su = ((const uint_t*)(hw + (size_t)i * OUT_CH))[l];
    float ax = bf16lo_to_f32(su), ay = bf16hi_to_f32(su);
    int e0 = row_start[i], e1 = row_start[i + 1];
    int e = e0;
    for (; e + 8 <= e1; e += 8) {
        int s[8];
        #pragma unroll
        for (int j = 0; j < 8; j++) s[j] = csr_src[e + j];
        uint_t v[8];
        #pragma unroll
        for (int j = 0; j < 8; j++)
            v[j] = ((const uint_t*)(hw + (size_t)s[j] * OUT_CH))[l];
        #pragma unroll
        for (int j = 0; j < 8; j++) {
            ax += bf16lo_to_f32(v[j]);
            ay += bf16hi_to_f32(v[j]);
        }
    }
    if (e < e1) {
        int last = e1 - 1;
        int s[8];
        #pragma unroll
        for (int j = 0; j < 8; j++) {
            int idx = e + j;
            s[j] = csr_src[idx <= last ? idx : last];
        }
        uint_t v[8];
        #pragma unroll
        for (int j = 0; j < 8; j++)
            v[j] = ((const uint_t*)(hw + (size_t)s[j] * OUT_CH))[l];
        #pragma unroll
        for (int j = 0; j < 8; j++) {
            float c = (e + j <= last) ? 1.0f : 0.0f;
            ax = fmaf(bf16lo_to_f32(v[j]), c, ax);
            ay = fmaf(bf16hi_to_f32(v[j]), c, ay);
        }
    }
    ax = fmaf(ax, di, b2[l * 2]);
    ay = fmaf(ay, di, b2[l * 2 + 1]);
    ((float2*)(out + (size_t)i * OUT_CH))[l] = make_float2(ax, ay);
}

extern "C" void kernel_launch(void* const* d_in, const int* in_sizes, int n_in,
                              void* d_out, int out_size, void* d_ws, size_t ws_size,
                              hipStream_t stream) {
    const float* x  = (const float*)d_in[0];
    const int*   ei = (const int*)d_in[1];
    const float* W1 = (const float*)d_in[2];
    const float* b1 = (const float*)d_in[3];
    const float* W2 = (const float*)d_in[4];
    const float* b2 = (const float*)d_in[5];
    float* out = (float*)d_out;

    const int N = in_sizes[0] / IN_CH;     // 100000
    const int E = in_sizes[1] / 2;         // 1600000
    const int* src = ei;
    const int* dst = ei + E;
    const int NB = (N + 63) / 64;          // buckets (1563)
    const int chunk = (E + NBLK - 1) / NBLK;

    // ---- workspace carve ----
    char* base = (char*)d_ws;
    size_t off = 0;
    auto alloc = [&](size_t bytes) -> void* {
        void* p = base + off;
        off = (off + bytes + 255) & ~(size_t)255;
        return p;
    };
    int*      blk_cnt     = (int*)alloc((size_t)NBLK * NB * 4);
    int*      blk_start   = (int*)alloc((size_t)NBLK * NB * 4);
    int*      btot        = (int*)alloc((size_t)NB * 4);
    int*      bucket_base = (int*)alloc((size_t)(NB + 1) * 4);
    int*      row_start   = (int*)alloc((size_t)(N + 1) * 4);
    float*    dinv        = (float*)alloc((size_t)N * 4);
    int*      csr_src     = (int*)alloc((size_t)E * 4);
    uint_t*   pairs       = (uint_t*)alloc((size_t)E * 4);
    ushort_t* xw          = (ushort_t*)alloc((size_t)N * HID * 2);
    ushort_t* h           = (ushort_t*)alloc((size_t)N * HID * 2);
    ushort_t* hw          = (ushort_t*)alloc((size_t)N * OUT_CH * 2);
    ushort_t* w1h         = (ushort_t*)alloc((size_t)128 * 128 * 2);
    ushort_t* w1l         = (ushort_t*)alloc((size_t)128 * 128 * 2);
    ushort_t* w2h         = (ushort_t*)alloc((size_t)64 * 128 * 2);
    ushort_t* w2l         = (ushort_t*)alloc((size_t)64 * 128 * 2);
    (void)ws_size;

    // W splits (tiny)
    wsplit_kernel<<<(128 * 128 + 64 * 128 + 255) / 256, 256, 0, stream>>>(
        W1, W2, w1h, w1l, w2h, w2l);

    // CSR build -- no global atomics anywhere
    hist_kernel<<<NBLK, 256, 0, stream>>>(dst, E, chunk, NB, blk_cnt);
    btot_kernel<<<(NB + 255) / 256, 256, 0, stream>>>(blk_cnt, NB, btot);
    scan_kernel<<<1, 256, 0, stream>>>(btot, NB, bucket_base, row_start, N, E);
    colscan_kernel<<<(NB + 15) / 16, 256, 0, stream>>>(blk_cnt, bucket_base, NB, blk_start);
    scatter_kernel<<<NBLK, 256, 0, stream>>>(src, dst, E, chunk, NB, blk_start, pairs);
    fine_fill_kernel<<<NB, 256, 0, stream>>>(pairs, bucket_base, row_start, dinv,
                                             csr_src, N);

    // layer 1 (MFMA, 3-term hi/lo split; xw pre-scaled by dinv[row])
    mfma_gemm_kernel<128, true><<<(N + 127) / 128, 256, 0, stream>>>(
        x, w1h, w1l, dinv, xw, N);
    agg1_kernel<<<(N * 64 + 255) / 256, 256, 0, stream>>>(xw, csr_src, row_start,
                                                          dinv, b1, h, N);
    // layer 2 (MFMA, 2-term; hw pre-scaled by dinv[row])
    mfma_gemm_kernel<64, false><<<(N + 127) / 128, 256, 0, stream>>>(
        h, w2h, w2l, dinv, hw, N);
    int waves2 = (N + 1) / 2;
    agg2_kernel<<<(waves2 * 64 + 255) / 256, 256, 0, stream>>>(hw, csr_src, row_start,
                                                               dinv, b2, out, N);
}

// Round 12
// 288.834 us; speedup vs baseline: 1.1075x; 1.0036x over previous
//
#include <hip/hip_runtime.h>
#include <hip/hip_bf16.h>

// GCN encoder: 2x GCNConv, symmetric norm, relu + L2 rownorm between.
// Pull aggregation over CSR-by-dst, bf16 intermediates (f32 accumulate).
// R7: CSR built with ZERO global atomics (LDS histograms + scans).
// R8: agg loops fully batched; dinv[src] folded into GEMM epilogue.
// R9: GEMMs on MFMA 16x16x32 bf16, hi/lo split (f32-equiv accuracy).
// R10: B staged in XOR-swizzled LDS; 2 row-tiles/wave. GEMMs off the radar.
// R11: agg1 16B/lane gather: NEUTRAL => not VALU-bound.
// R12: 4 gather chains: +5% => ~3.5 TB/s L2-miss-path ceiling.
// R13: channel-half split REGRESSED: misses are compulsory random-line
//      traffic (cross-XCD duplication: FETCH ~ 8 x 24MB = 190MB, structural).
// R14: agg2 32-edge-iter port REGRESSED (tail-dominated at degree 16).
// R15: grid-stride persistent waves REGRESSED (block churn IS the balancer).
// R16: best-measured components; 289.9us. agg1 62.5us = within 2.5% of its
//      fabric floor ((190MB+25MB)/3.5TB/s ~ 61us). Counter-verified.
// R17 (this round): launch-gap probe -- wsplit fused into hist (independent
// work, same grid; one dispatch+gap removed), all else frozen. Neutral
// result => gaps negligible => pipeline at practical floor.

#define IN_CH 128
#define HID 128
#define OUT_CH 64
#define NBLK 128          // chunk blocks for hist/scatter
#define MAXNB 1568        // >= ceil(100000/64)=1563 buckets

typedef unsigned int uint_t;
typedef unsigned short ushort_t;
typedef __attribute__((ext_vector_type(8))) short bf16x8;
typedef __attribute__((ext_vector_type(4))) float f32x4;
typedef __attribute__((ext_vector_type(2))) float f32v2;

__device__ __forceinline__ ushort_t f32_to_bf16_rn(float f) {
    uint_t u = __float_as_uint(f);
    u = (u + 0x7fffu + ((u >> 16) & 1u)) >> 16;
    return (ushort_t)u;
}
__device__ __forceinline__ float bf16lo_to_f32(uint_t u) { return __uint_as_float(u << 16); }
__device__ __forceinline__ float bf16hi_to_f32(uint_t u) { return __uint_as_float(u & 0xffff0000u); }

// accumulate one 16B row-chunk (8 bf16 channels) into 4 f32v2 accumulators
__device__ __forceinline__ void acc_row(f32v2& a0, f32v2& a1, f32v2& a2, f32v2& a3,
                                        uint4 v) {
    a0 += (f32v2){bf16lo_to_f32(v.x), bf16hi_to_f32(v.x)};
    a1 += (f32v2){bf16lo_to_f32(v.y), bf16hi_to_f32(v.y)};
    a2 += (f32v2){bf16lo_to_f32(v.z), bf16hi_to_f32(v.z)};
    a3 += (f32v2){bf16lo_to_f32(v.w), bf16hi_to_f32(v.w)};
}
__device__ __forceinline__ void acc_row_c(f32v2& a0, f32v2& a1, f32v2& a2, f32v2& a3,
                                          uint4 v, float c) {
    f32v2 cv = {c, c};
    a0 += (f32v2){bf16lo_to_f32(v.x), bf16hi_to_f32(v.x)} * cv;
    a1 += (f32v2){bf16lo_to_f32(v.y), bf16hi_to_f32(v.y)} * cv;
    a2 += (f32v2){bf16lo_to_f32(v.z), bf16hi_to_f32(v.z)} * cv;
    a3 += (f32v2){bf16lo_to_f32(v.w), bf16hi_to_f32(v.w)} * cv;
}

// ---------------- phase 1: per-block LDS bucket histogram (+ fused W split) -------
// R17: wsplit fused as an independent pre-pass (idx < 24576 over 128x256 threads).
// w1h/w1l: [128 cols][128 k]; w2h/w2l: [64 cols][128 k]. Wt[c][k] = W[k][c].
__global__ __launch_bounds__(256) void hist_kernel(const int* __restrict__ dst, int E,
                                                   int chunk, int NB,
                                                   int* __restrict__ blk_cnt,
                                                   const float* __restrict__ W1,
                                                   const float* __restrict__ W2,
                                                   ushort_t* __restrict__ w1h,
                                                   ushort_t* __restrict__ w1l,
                                                   ushort_t* __restrict__ w2h,
                                                   ushort_t* __restrict__ w2l) {
    __shared__ int hist[MAXNB];
    int tid = threadIdx.x;
    int blk = blockIdx.x;

    // ---- fused wsplit: independent global work, no barrier interaction ----
    {
        int idx = blk * 256 + tid;
        const int tot1 = 128 * 128;
        const int tot = tot1 + 64 * 128;
        if (idx < tot) {
            float v;
            ushort_t* ph;
            ushort_t* pl;
            int o;
            if (idx < tot1) {
                int c = idx >> 7, k = idx & 127;
                v = W1[k * 128 + c];
                ph = w1h; pl = w1l; o = idx;
            } else {
                int j = idx - tot1;
                int c = j >> 7, k = j & 127;
                v = W2[k * 64 + c];
                ph = w2h; pl = w2l; o = j;
            }
            ushort_t hh = f32_to_bf16_rn(v);
            float hv = __uint_as_float((uint_t)hh << 16);
            ph[o] = hh;
            pl[o] = f32_to_bf16_rn(v - hv);
        }
    }

    for (int b = tid; b < NB; b += 256) hist[b] = 0;
    __syncthreads();
    int start = blk * chunk;
    int end = start + chunk; if (end > E) end = E;
    int e = start + tid;
    for (; e + 768 < end; e += 1024) {
        int d0 = dst[e], d1 = dst[e + 256], d2 = dst[e + 512], d3 = dst[e + 768];
        atomicAdd(&hist[d0 >> 6], 1);
        atomicAdd(&hist[d1 >> 6], 1);
        atomicAdd(&hist[d2 >> 6], 1);
        atomicAdd(&hist[d3 >> 6], 1);
    }
    for (; e < end; e += 256) atomicAdd(&hist[dst[e] >> 6], 1);
    __syncthreads();
    for (int b = tid; b < NB; b += 256) blk_cnt[blk * NB + b] = hist[b];
}

// ---------------- phase 2a: bucket totals (column sums) ----------------
__global__ __launch_bounds__(256) void btot_kernel(const int* __restrict__ blk_cnt,
                                                   int NB, int* __restrict__ btot) {
    int b = blockIdx.x * 256 + threadIdx.x;
    if (b < NB) {
        int sum = 0;
        #pragma unroll 8
        for (int blk = 0; blk < NBLK; blk++) sum += blk_cnt[blk * NB + b];
        btot[b] = sum;
    }
}

// ---------------- phase 2b: single-block exclusive scan over buckets --------------
__global__ __launch_bounds__(256) void scan_kernel(const int* __restrict__ btot, int NB,
                                                   int* __restrict__ bucket_base,
                                                   int* __restrict__ row_start,
                                                   int n, int E) {
    __shared__ int sdata[256];
    __shared__ int carryS;
    int tid = threadIdx.x;
    if (tid == 0) carryS = 0;
    __syncthreads();
    int nchunks = (NB + 255) / 256;
    for (int c = 0; c < nchunks; c++) {
        int i = c * 256 + tid;
        int v = (i < NB) ? btot[i] : 0;
        sdata[tid] = v;
        __syncthreads();
        for (int off = 1; off < 256; off <<= 1) {
            int t = (tid >= off) ? sdata[tid - off] : 0;
            __syncthreads();
            sdata[tid] += t;
            __syncthreads();
        }
        if (i < NB) bucket_base[i] = carryS + sdata[tid] - v;
        __syncthreads();
        if (tid == 0) carryS += sdata[255];
        __syncthreads();
    }
    if (tid == 0) {
        bucket_base[NB] = E;
        row_start[n] = E;
    }
}

// ---------------- phase 2c: per-bucket exclusive scan over blocks -----------------
__global__ __launch_bounds__(256) void colscan_kernel(const int* __restrict__ blk_cnt,
                                                      const int* __restrict__ bucket_base,
                                                      int NB, int* __restrict__ blk_start) {
    __shared__ int tile[NBLK][16];
    int tid = threadIdx.x;
    int b0 = blockIdx.x * 16;
    for (int idx = tid; idx < NBLK * 16; idx += 256) {
        int blk = idx >> 4, b = idx & 15;
        if (b0 + b < NB) tile[blk][b] = blk_cnt[blk * NB + b0 + b];
    }
    __syncthreads();
    if (tid < 16 && b0 + tid < NB) {
        int running = bucket_base[b0 + tid];
        for (int blk = 0; blk < NBLK; blk++) {
            int t = tile[blk][tid];
            tile[blk][tid] = running;
            running += t;
        }
    }
    __syncthreads();
    for (int idx = tid; idx < NBLK * 16; idx += 256) {
        int blk = idx >> 4, b = idx & 15;
        if (b0 + b < NB) blk_start[blk * NB + b0 + b] = tile[blk][b];
    }
}

// ---------------- phase 3: scatter, LDS tickets only ----------------
// pack: src (26 bits) | (dst & 63) << 26.
__global__ __launch_bounds__(256) void scatter_kernel(const int* __restrict__ src,
                                                      const int* __restrict__ dst,
                                                      int E, int chunk, int NB,
                                                      const int* __restrict__ blk_start,
                                                      uint_t* __restrict__ pairs) {
    __shared__ int cur[MAXNB];
    int tid = threadIdx.x;
    int blk = blockIdx.x;
    for (int b = tid; b < NB; b += 256) cur[b] = blk_start[blk * NB + b];
    __syncthreads();
    int start = blk * chunk;
    int end = start + chunk; if (end > E) end = E;
    int e = start + tid;
    for (; e + 768 < end; e += 1024) {
        int d0 = dst[e], d1 = dst[e + 256], d2 = dst[e + 512], d3 = dst[e + 768];
        int s0 = src[e], s1 = src[e + 256], s2 = src[e + 512], s3 = src[e + 768];
        int p0 = atomicAdd(&cur[d0 >> 6], 1);
        int p1 = atomicAdd(&cur[d1 >> 6], 1);
        int p2 = atomicAdd(&cur[d2 >> 6], 1);
        int p3 = atomicAdd(&cur[d3 >> 6], 1);
        pairs[p0] = (uint_t)s0 | ((uint_t)(d0 & 63) << 26);
        pairs[p1] = (uint_t)s1 | ((uint_t)(d1 & 63) << 26);
        pairs[p2] = (uint_t)s2 | ((uint_t)(d2 & 63) << 26);
        pairs[p3] = (uint_t)s3 | ((uint_t)(d3 & 63) << 26);
    }
    for (; e < end; e += 256) {
        int d = dst[e], s = src[e];
        int p = atomicAdd(&cur[d >> 6], 1);
        pairs[p] = (uint_t)s | ((uint_t)(d & 63) << 26);
    }
}

// ---------------- phase 4: fine fill -- per bucket: counts, row_start, dinv, csr ---
__global__ __launch_bounds__(256) void fine_fill_kernel(const uint_t* __restrict__ pairs,
                                                        const int* __restrict__ bucket_base,
                                                        int* __restrict__ row_start,
                                                        float* __restrict__ dinv,
                                                        int* __restrict__ csr_src,
                                                        int n) {
    __shared__ int cnt64[64];
    __shared__ int cur[64];
    int b = blockIdx.x;
    int node0 = b << 6;
    int tid = threadIdx.x;
    if (tid < 64) cnt64[tid] = 0;
    __syncthreads();
    int start = bucket_base[b];
    int end = bucket_base[b + 1];
    int e = start + tid;
    for (; e + 768 < end; e += 1024) {
        uint_t u0 = pairs[e], u1 = pairs[e + 256], u2 = pairs[e + 512], u3 = pairs[e + 768];
        atomicAdd(&cnt64[u0 >> 26], 1);
        atomicAdd(&cnt64[u1 >> 26], 1);
        atomicAdd(&cnt64[u2 >> 26], 1);
        atomicAdd(&cnt64[u3 >> 26], 1);
    }
    for (; e < end; e += 256) atomicAdd(&cnt64[pairs[e] >> 26], 1);
    __syncthreads();
    if (tid < 64) {
        int c = cnt64[tid];
        int v = c;
        #pragma unroll
        for (int off = 1; off < 64; off <<= 1) {
            int u = __shfl_up(v, off, 64);
            if (tid >= off) v += u;
        }
        int excl = start + v - c;
        if (node0 + tid < n) {
            row_start[node0 + tid] = excl;
            dinv[node0 + tid] = rsqrtf((float)(c + 1));  // +1 self loop
        }
        cur[tid] = excl;
    }
    __syncthreads();
    e = start + tid;
    for (; e + 768 < end; e += 1024) {
        uint_t u0 = pairs[e], u1 = pairs[e + 256], u2 = pairs[e + 512], u3 = pairs[e + 768];
        int p0 = atomicAdd(&cur[u0 >> 26], 1);
        int p1 = atomicAdd(&cur[u1 >> 26], 1);
        int p2 = atomicAdd(&cur[u2 >> 26], 1);
        int p3 = atomicAdd(&cur[u3 >> 26], 1);
        csr_src[p0] = (int)(u0 & 0x3FFFFFFu);
        csr_src[p1] = (int)(u1 & 0x3FFFFFFu);
        csr_src[p2] = (int)(u2 & 0x3FFFFFFu);
        csr_src[p3] = (int)(u3 & 0x3FFFFFFu);
    }
    for (; e < end; e += 256) {
        uint_t u = pairs[e];
        int p = atomicAdd(&cur[u >> 26], 1);
        csr_src[p] = (int)(u & 0x3FFFFFFu);
    }
}

// ---------------- MFMA GEMM: Y[n x NCOL] = (X[n x 128] @ W) * rowscale[row] -------
// hi/lo split: F32_IN: 3 terms (xh*wh + xh*wl + xl*wh); bf16 in: 2 terms (exact A).
// B staged in XOR-swizzled LDS (byte ^= (row&7)<<4): conflict-free ds_read_b128,
// no L1 thrash. 4 waves x 32 rows = 128 rows/block; 2 row-tiles/wave for ILP.
// Fragment maps (v_mfma_f32_16x16x32_bf16): A row=lane&15, k=(lane>>4)*8+j;
// B col=lane&15, k=(lane>>4)*8+j; D col=lane&15, row=(lane>>4)*4+reg.
template <int NCOL, bool F32_IN>
__global__ __launch_bounds__(256, 2) void mfma_gemm_kernel(const void* __restrict__ Xv,
                                                           const ushort_t* __restrict__ Wth,
                                                           const ushort_t* __restrict__ Wtl,
                                                           const float* __restrict__ rowscale,
                                                           ushort_t* __restrict__ Y, int n) {
    constexpr int NT = NCOL / 16;          // col tiles (8 or 4)
    constexpr int WB = NCOL * 128 * 2;     // bytes per W array (h or l)
    constexpr int NCH = WB / 16;           // 16B chunks per array
    __shared__ __align__(16) char Bs[2 * WB];   // h @0, l @WB; swizzled

    int tid = threadIdx.x;

    // ---- stage B, swizzled (reg-staged: global_load_lds can't swizzle) ----
    for (int i = tid; i < 2 * NCH; i += 256) {
        bool lo = (i >= NCH);
        int j = lo ? i - NCH : i;
        int row = j >> 4, c = j & 15;        // row = W col index; 16 chunks/row
        bf16x8 v = *(const bf16x8*)((lo ? Wtl : Wth) + row * 128 + c * 8);
        int bo = (row << 8) + (c << 4);
        bo ^= (row & 7) << 4;                // T2 swizzle
        *(bf16x8*)(Bs + (lo ? WB : 0) + bo) = v;
    }
    __syncthreads();

    int wave = tid >> 6;
    int lane = tid & 63;
    int q = lane >> 4;                       // k-quarter selector
    int r16 = lane & 15;                     // A row / B,D col within tile
    int rowBase = blockIdx.x * 128 + wave * 32;
    int ar0 = rowBase + r16;      if (ar0 > n - 1) ar0 = n - 1;
    int ar1 = rowBase + 16 + r16; if (ar1 > n - 1) ar1 = n - 1;

    const float* X = (const float*)Xv;
    const ushort_t* Hb = (const ushort_t*)Xv;

    f32x4 acc[2][NT];
    #pragma unroll
    for (int rt = 0; rt < 2; rt++)
        #pragma unroll
        for (int t = 0; t < NT; t++) acc[rt][t] = (f32x4){0.f, 0.f, 0.f, 0.f};

    #pragma unroll
    for (int ks = 0; ks < 4; ks++) {
        int k0 = ks * 32 + q * 8;            // element index in K
        bf16x8 ah[2], al[2] = {};
        #pragma unroll
        for (int rt = 0; rt < 2; rt++) {
            int arow = rt ? ar1 : ar0;
            if (F32_IN) {
                const float4* xr = (const float4*)(X + (size_t)arow * 128 + k0);
                float4 p0 = xr[0], p1 = xr[1];
                float v[8] = {p0.x, p0.y, p0.z, p0.w, p1.x, p1.y, p1.z, p1.w};
                #pragma unroll
                for (int j = 0; j < 8; j++) {
                    ushort_t hb = f32_to_bf16_rn(v[j]);
                    float hv = __uint_as_float((uint_t)hb << 16);
                    ah[rt][j] = (short)hb;
                    al[rt][j] = (short)f32_to_bf16_rn(v[j] - hv);
                }
            } else {
                ah[rt] = *(const bf16x8*)(Hb + (size_t)arow * 128 + k0);
            }
        }
        #pragma unroll
        for (int t = 0; t < NT; t++) {
            int bo = ((t * 16 + r16) << 8) + ks * 64 + (q << 4);
            bo ^= (r16 & 7) << 4;            // (t*16+r16)&7 == r16&7
            bf16x8 bh = *(const bf16x8*)(Bs + bo);
            bf16x8 bl = *(const bf16x8*)(Bs + WB + bo);
            #pragma unroll
            for (int rt = 0; rt < 2; rt++) {
                acc[rt][t] = __builtin_amdgcn_mfma_f32_16x16x32_bf16(ah[rt], bh, acc[rt][t], 0, 0, 0);
                acc[rt][t] = __builtin_amdgcn_mfma_f32_16x16x32_bf16(ah[rt], bl, acc[rt][t], 0, 0, 0);
                if (F32_IN)
                    acc[rt][t] = __builtin_amdgcn_mfma_f32_16x16x32_bf16(al[rt], bh, acc[rt][t], 0, 0, 0);
            }
        }
    }

    #pragma unroll
    for (int rt = 0; rt < 2; rt++) {
        #pragma unroll
        for (int rr = 0; rr < 4; rr++) {
            int row = rowBase + rt * 16 + q * 4 + rr;
            if (row < n) {
                float rs = rowscale[row];
                #pragma unroll
                for (int t = 0; t < NT; t++)
                    Y[(size_t)row * NCOL + t * 16 + r16] = f32_to_bf16_rn(acc[rt][t][rr] * rs);
            }
        }
    }
}

// ---------------- aggregation layer 1: pull + bias + relu + L2 rownorm ----------------
// xw rows pre-scaled by dinv[src]; result = dinv[i]*(self + sum) + b1.
// R12 body (best measured 62.3us): 16B/lane gather, 16 row-chunk lanes,
// 4 edge-groups x 4 independent gather chains; masked clamped tail.
__global__ __launch_bounds__(256) void agg1_kernel(const ushort_t* __restrict__ xw,
                                                   const int* __restrict__ csr_src,
                                                   const int* __restrict__ row_start,
                                                   const float* __restrict__ dinv,
                                                   const float* __restrict__ b1,
                                                   ushort_t* __restrict__ h, int n) {
    int wid = (blockIdx.x * 256 + threadIdx.x) >> 6;
    int lane = threadIdx.x & 63;
    if (wid >= n) return;
    int i = wid;
    int g = lane >> 4;
    int cb = lane & 15;
    const uint4* X4 = (const uint4*)xw;      // row i = X4[i*16 + cb]
    float di = dinv[i];
    int e0 = row_start[i], e1 = row_start[i + 1];

    f32v2 a0 = {0.f, 0.f}, a1 = {0.f, 0.f}, a2 = {0.f, 0.f}, a3 = {0.f, 0.f};
    // self row: group 0 contributes once
    {
        uint4 v = X4[(size_t)i * 16 + cb];
        acc_row_c(a0, a1, a2, a3, v, (g == 0) ? 1.0f : 0.0f);
    }
    int e = e0;
    // main loop: 16 edges/iter, 4 independent idx->gather chains in flight
    for (; e + 16 <= e1; e += 16) {
        int s0 = csr_src[e + g];
        int s1 = csr_src[e + 4 + g];
        int s2 = csr_src[e + 8 + g];
        int s3 = csr_src[e + 12 + g];
        uint4 v0 = X4[(size_t)s0 * 16 + cb];
        uint4 v1 = X4[(size_t)s1 * 16 + cb];
        uint4 v2 = X4[(size_t)s2 * 16 + cb];
        uint4 v3 = X4[(size_t)s3 * 16 + cb];
        acc_row(a0, a1, a2, a3, v0);
        acc_row(a0, a1, a2, a3, v1);
        acc_row(a0, a1, a2, a3, v2);
        acc_row(a0, a1, a2, a3, v3);
    }
    // masked tail: same 4-chain layout, positions clamped to last
    if (e < e1) {
        int last = e1 - 1;
        int p0 = e + g, p1 = e + 4 + g, p2 = e + 8 + g, p3 = e + 12 + g;
        int s0 = csr_src[p0 <= last ? p0 : last];
        int s1 = csr_src[p1 <= last ? p1 : last];
        int s2 = csr_src[p2 <= last ? p2 : last];
        int s3 = csr_src[p3 <= last ? p3 : last];
        uint4 v0 = X4[(size_t)s0 * 16 + cb];
        uint4 v1 = X4[(size_t)s1 * 16 + cb];
        uint4 v2 = X4[(size_t)s2 * 16 + cb];
        uint4 v3 = X4[(size_t)s3 * 16 + cb];
        acc_row_c(a0, a1, a2, a3, v0, (p0 <= last) ? 1.0f : 0.0f);
        acc_row_c(a0, a1, a2, a3, v1, (p1 <= last) ? 1.0f : 0.0f);
        acc_row_c(a0, a1, a2, a3, v2, (p2 <= last) ? 1.0f : 0.0f);
        acc_row_c(a0, a1, a2, a3, v3, (p3 <= last) ? 1.0f : 0.0f);
    }
    // combine the 4 edge-groups
    #pragma unroll
    for (int m = 16; m <= 32; m <<= 1) {
        a0.x += __shfl_xor(a0.x, m, 64); a0.y += __shfl_xor(a0.y, m, 64);
        a1.x += __shfl_xor(a1.x, m, 64); a1.y += __shfl_xor(a1.y, m, 64);
        a2.x += __shfl_xor(a2.x, m, 64); a2.y += __shfl_xor(a2.y, m, 64);
        a3.x += __shfl_xor(a3.x, m, 64); a3.y += __shfl_xor(a3.y, m, 64);
    }
    // bias + relu for channels cb*8 .. cb*8+7
    const float2* bp = (const float2*)(b1 + cb * 8);
    float2 b0v = bp[0], b1v = bp[1], b2v = bp[2], b3v = bp[3];
    float vals[8];
    vals[0] = fmaxf(fmaf(a0.x, di, b0v.x), 0.f);
    vals[1] = fmaxf(fmaf(a0.y, di, b0v.y), 0.f);
    vals[2] = fmaxf(fmaf(a1.x, di, b1v.x), 0.f);
    vals[3] = fmaxf(fmaf(a1.y, di, b1v.y), 0.f);
    vals[4] = fmaxf(fmaf(a2.x, di, b2v.x), 0.f);
    vals[5] = fmaxf(fmaf(a2.y, di, b2v.y), 0.f);
    vals[6] = fmaxf(fmaf(a3.x, di, b3v.x), 0.f);
    vals[7] = fmaxf(fmaf(a3.y, di, b3v.y), 0.f);
    float ss = 0.f;
    #pragma unroll
    for (int j = 0; j < 8; j++) ss = fmaf(vals[j], vals[j], ss);
    #pragma unroll
    for (int m = 1; m <= 8; m <<= 1) ss += __shfl_xor(ss, m, 64);
    float scale = 1.0f / fmaxf(sqrtf(ss), 1e-12f);
    if (g == 0) {
        uint4 o;
        o.x = (uint_t)f32_to_bf16_rn(vals[0] * scale) | ((uint_t)f32_to_bf16_rn(vals[1] * scale) << 16);
        o.y = (uint_t)f32_to_bf16_rn(vals[2] * scale) | ((uint_t)f32_to_bf16_rn(vals[3] * scale) << 16);
        o.z = (uint_t)f32_to_bf16_rn(vals[4] * scale) | ((uint_t)f32_to_bf16_rn(vals[5] * scale) << 16);
        o.w = (uint_t)f32_to_bf16_rn(vals[6] * scale) | ((uint_t)f32_to_bf16_rn(vals[7] * scale) << 16);
        ((uint4*)h)[(size_t)i * 16 + cb] = o;
    }
}

// ---------------- aggregation layer 2: pull + bias -> d_out (f32) ----------------
// hw rows pre-scaled by dinv[src]; result = dinv[i]*(self + sum) + b2.
// R10-measured body: 2 nodes/wave, 32 lanes each, 8-edge batches, masked tail.
__global__ __launch_bounds__(256) void agg2_kernel(const ushort_t* __restrict__ hw,
                                                   const int* __restrict__ csr_src,
                                                   const int* __restrict__ row_start,
                                                   const float* __restrict__ dinv,
                                                   const float* __restrict__ b2,
                                                   float* __restrict__ out, int n) {
    int wid = (blockIdx.x * 256 + threadIdx.x) >> 6;
    int lane = threadIdx.x & 63;
    int i = wid * 2 + (lane >> 5);
    int l = lane & 31;
    if (i >= n) return;
    float di = dinv[i];
    uint_t su = ((const uint_t*)(hw + (size_t)i * OUT_CH))[l];
    float ax = bf16lo_to_f32(su), ay = bf16hi_to_f32(su);
    int e0 = row_start[i], e1 = row_start[i + 1];
    int e = e0;
    for (; e + 8 <= e1; e += 8) {
        int s[8];
        #pragma unroll
        for (int j = 0; j < 8; j++) s[j] = csr_src[e + j];
        uint_t v[8];
        #pragma unroll
        for (int j = 0; j < 8; j++)
            v[j] = ((const uint_t*)(hw + (size_t)s[j] * OUT_CH))[l];
        #pragma unroll
        for (int j = 0; j < 8; j++) {
            ax += bf16lo_to_f32(v[j]);
            ay += bf16hi_to_f32(v[j]);
        }
    }
    if (e < e1) {
        int last = e1 - 1;
        int s[8];
        #pragma unroll
        for (int j = 0; j < 8; j++) {
            int idx = e + j;
            s[j] = csr_src[idx <= last ? idx : last];
        }
        uint_t v[8];
        #pragma unroll
        for (int j = 0; j < 8; j++)
            v[j] = ((const uint_t*)(hw + (size_t)s[j] * OUT_CH))[l];
        #pragma unroll
        for (int j = 0; j < 8; j++) {
            float c = (e + j <= last) ? 1.0f : 0.0f;
            ax = fmaf(bf16lo_to_f32(v[j]), c, ax);
            ay = fmaf(bf16hi_to_f32(v[j]), c, ay);
        }
    }
    ax = fmaf(ax, di, b2[l * 2]);
    ay = fmaf(ay, di, b2[l * 2 + 1]);
    ((float2*)(out + (size_t)i * OUT_CH))[l] = make_float2(ax, ay);
}

extern "C" void kernel_launch(void* const* d_in, const int* in_sizes, int n_in,
                              void* d_out, int out_size, void* d_ws, size_t ws_size,
                              hipStream_t stream) {
    const float* x  = (const float*)d_in[0];
    const int*   ei = (const int*)d_in[1];
    const float* W1 = (const float*)d_in[2];
    const float* b1 = (const float*)d_in[3];
    const float* W2 = (const float*)d_in[4];
    const float* b2 = (const float*)d_in[5];
    float* out = (float*)d_out;

    const int N = in_sizes[0] / IN_CH;     // 100000
    const int E = in_sizes[1] / 2;         // 1600000
    const int* src = ei;
    const int* dst = ei + E;
    const int NB = (N + 63) / 64;          // buckets (1563)
    const int chunk = (E + NBLK - 1) / NBLK;

    // ---- workspace carve ----
    char* base = (char*)d_ws;
    size_t off = 0;
    auto alloc = [&](size_t bytes) -> void* {
        void* p = base + off;
        off = (off + bytes + 255) & ~(size_t)255;
        return p;
    };
    int*      blk_cnt     = (int*)alloc((size_t)NBLK * NB * 4);
    int*      blk_start   = (int*)alloc((size_t)NBLK * NB * 4);
    int*      btot        = (int*)alloc((size_t)NB * 4);
    int*      bucket_base = (int*)alloc((size_t)(NB + 1) * 4);
    int*      row_start   = (int*)alloc((size_t)(N + 1) * 4);
    float*    dinv        = (float*)alloc((size_t)N * 4);
    int*      csr_src     = (int*)alloc((size_t)E * 4);
    uint_t*   pairs       = (uint_t*)alloc((size_t)E * 4);
    ushort_t* xw          = (ushort_t*)alloc((size_t)N * HID * 2);
    ushort_t* h           = (ushort_t*)alloc((size_t)N * HID * 2);
    ushort_t* hw          = (ushort_t*)alloc((size_t)N * OUT_CH * 2);
    ushort_t* w1h         = (ushort_t*)alloc((size_t)128 * 128 * 2);
    ushort_t* w1l         = (ushort_t*)alloc((size_t)128 * 128 * 2);
    ushort_t* w2h         = (ushort_t*)alloc((size_t)64 * 128 * 2);
    ushort_t* w2l         = (ushort_t*)alloc((size_t)64 * 128 * 2);
    (void)ws_size;

    // CSR build -- no global atomics anywhere (wsplit fused into hist, R17)
    hist_kernel<<<NBLK, 256, 0, stream>>>(dst, E, chunk, NB, blk_cnt,
                                          W1, W2, w1h, w1l, w2h, w2l);
    btot_kernel<<<(NB + 255) / 256, 256, 0, stream>>>(blk_cnt, NB, btot);
    scan_kernel<<<1, 256, 0, stream>>>(btot, NB, bucket_base, row_start, N, E);
    colscan_kernel<<<(NB + 15) / 16, 256, 0, stream>>>(blk_cnt, bucket_base, NB, blk_start);
    scatter_kernel<<<NBLK, 256, 0, stream>>>(src, dst, E, chunk, NB, blk_start, pairs);
    fine_fill_kernel<<<NB, 256, 0, stream>>>(pairs, bucket_base, row_start, dinv,
                                             csr_src, N);

    // layer 1 (MFMA, 3-term hi/lo split; xw pre-scaled by dinv[row])
    mfma_gemm_kernel<128, true><<<(N + 127) / 128, 256, 0, stream>>>(
        x, w1h, w1l, dinv, xw, N);
    agg1_kernel<<<(N * 64 + 255) / 256, 256, 0, stream>>>(xw, csr_src, row_start,
                                                          dinv, b1, h, N);
    // layer 2 (MFMA, 2-term; hw pre-scaled by dinv[row])
    mfma_gemm_kernel<64, false><<<(N + 127) / 128, 256, 0, stream>>>(
        h, w2h, w2l, dinv, hw, N);
    int waves2 = (N + 1) / 2;
    agg2_kernel<<<(waves2 * 64 + 255) / 256, 256, 0, stream>>>(hw, csr_src, row_start,
                                                               dinv, b2, out, N);
}